// Round 4
// baseline (533.389 us; speedup 1.0000x reference)
//
#include <hip/hip_runtime.h>

typedef float    f32x4 __attribute__((ext_vector_type(4)));
typedef _Float16 f16x8 __attribute__((ext_vector_type(8)));
typedef _Float16 f16x4 __attribute__((ext_vector_type(4)));

#define T_TOK 4096
#define HD    1024
#define ID    4096
#define NE    8
#define TOTP  (2*T_TOK)
#define MAXT1 72     // BM=128 tiles
#define MAXT2 40     // BM=256 tiles

// ---- workspace layout (bytes). Total ~295 MB ----
#define WS_CNT   0
#define WS_FILL  64
#define WS_OFF   128
#define WS_TOT   192
#define WS_TOT2  196
#define WS_TEXP  256
#define WS_TM0   (256 + 4*MAXT1)
#define WS_TEXP2 (256 + 8*MAXT1)
#define WS_TM02  (256 + 8*MAXT1 + 4*MAXT2)
#define WS_TOPE  2048
#define WS_TOPW  (WS_TOPE + 4*TOTP)
#define WS_PAIR  (WS_TOPW + 4*TOTP)
#define WS_ACT   ((size_t)1 << 20)                              // f16[TOTP*ID]   64 MB
constexpr size_t WS_YBUF = WS_ACT  + 2ull*TOTP*ID;              // f16[TOTP*HD]   16 MB
constexpr size_t WS_HS16 = WS_YBUF + 2ull*TOTP*HD;              // f16[T*HD]       8 MB
constexpr size_t WS_WG16 = WS_HS16 + 2ull*T_TOK*HD;             // f16[E][I][H]   67 MB
constexpr size_t WS_WU16 = WS_WG16 + 2ull*NE*HD*ID;             // f16[E][I][H]   67 MB
constexpr size_t WS_WD16 = WS_WU16 + 2ull*NE*HD*ID;             // f16[E][H][I]   67 MB

// async global->LDS, 16B per lane, wave-uniform LDS base
__device__ __forceinline__ void gll16(const void* g, void* l) {
  __builtin_amdgcn_global_load_lds(
      (const __attribute__((address_space(1))) unsigned int*)g,
      (__attribute__((address_space(3))) unsigned int*)l, 16, 0, 0);
}

#define WAITV(N) do { \
    asm volatile("s_waitcnt vmcnt(" #N ")" ::: "memory"); \
    __builtin_amdgcn_sched_barrier(0); \
  } while (0)

// [row][32] f16 tile: 16B-granule XOR swizzle (2-way bank aliasing = free)
__device__ __forceinline__ int lofs(int row, int g) {
  return row * 32 + ((g ^ ((row >> 1) & 3)) << 3);
}

// ---------------- routing ----------------
__global__ void k_router(const float* __restrict__ logits, char* __restrict__ ws) {
  int t = blockIdx.x * blockDim.x + threadIdx.x;
  if (t >= T_TOK) return;
  float v0 = -1e30f, v1 = -1e30f; int i0 = 0, i1 = 0;
  #pragma unroll
  for (int e = 0; e < NE; ++e) {
    float v = logits[t * NE + e];
    if (v > v0)      { v1 = v0; i1 = i0; v0 = v; i0 = e; }
    else if (v > v1) { v1 = v;  i1 = e; }
  }
  float w0 = 1.f / (1.f + __expf(v1 - v0));
  ((int*)(ws + WS_TOPE))[2*t]   = i0;
  ((int*)(ws + WS_TOPE))[2*t+1] = i1;
  ((float*)(ws + WS_TOPW))[2*t]   = w0;
  ((float*)(ws + WS_TOPW))[2*t+1] = 1.f - w0;
  atomicAdd(&((int*)(ws + WS_CNT))[i0], 1);
  atomicAdd(&((int*)(ws + WS_CNT))[i1], 1);
}

__global__ void k_prefix(char* __restrict__ ws) {
  if (threadIdx.x != 0 || blockIdx.x != 0) return;
  const int* cnt = (const int*)(ws + WS_CNT);
  int* off   = (int*)(ws + WS_OFF);
  int* texp  = (int*)(ws + WS_TEXP);
  int* tm0   = (int*)(ws + WS_TM0);
  int* texp2 = (int*)(ws + WS_TEXP2);
  int* tm02  = (int*)(ws + WS_TM02);
  int run = 0, t1 = 0, t2 = 0;
  for (int e = 0; e < NE; ++e) {
    off[e] = run;
    int ne = cnt[e];
    for (int i = 0; i < ne; i += 128) { texp[t1] = e; tm0[t1] = i; ++t1; }
    for (int i = 0; i < ne; i += 256) { texp2[t2] = e; tm02[t2] = i; ++t2; }
    run += ne;
  }
  off[NE] = run;
  *(int*)(ws + WS_TOT)  = t1;
  *(int*)(ws + WS_TOT2) = t2;
}

__global__ void k_scatter(char* __restrict__ ws) {
  int t = blockIdx.x * blockDim.x + threadIdx.x;
  if (t >= T_TOK) return;
  const int* tope = (const int*)(ws + WS_TOPE);
  const int* off  = (const int*)(ws + WS_OFF);
  int* fill = (int*)(ws + WS_FILL);
  int* pair = (int*)(ws + WS_PAIR);
  #pragma unroll
  for (int s = 0; s < 2; ++s) {
    int id = 2*t + s;
    int e = tope[id];
    int pos = off[e] + atomicAdd(&fill[e], 1);
    pair[pos] = id;   // order nondeterministic; ybuf row = id keeps output deterministic
  }
}

// ---------------- conversions ----------------
__global__ void k_hscvt(const float* __restrict__ src, _Float16* __restrict__ dst) {
  int i = blockIdx.x * blockDim.x + threadIdx.x;
  f32x4 v = ((const f32x4*)src)[i];
  f16x4 o;
  #pragma unroll
  for (int j = 0; j < 4; ++j) o[j] = (_Float16)v[j];
  ((f16x4*)dst)[i] = o;
}

// f32 [e][K][N] -> f16 [e][N][K], 64x64 tiles via LDS
__global__ __launch_bounds__(256) void k_wtrans(const float* __restrict__ src,
                                                _Float16* __restrict__ dst,
                                                int K, int N) {
  const int e = blockIdx.z;
  const int n0 = blockIdx.x * 64, k0 = blockIdx.y * 64;
  const float* s = src + (size_t)e * K * N;
  _Float16* d = dst + (size_t)e * (size_t)K * N;
  __shared__ _Float16 t[64][68];
  const int tx = threadIdx.x & 15, ty = threadIdx.x >> 4;
  #pragma unroll
  for (int it = 0; it < 4; ++it) {
    int k = k0 + it*16 + ty;
    f32x4 v = *(const f32x4*)&s[(size_t)k * N + n0 + tx*4];
    #pragma unroll
    for (int j = 0; j < 4; ++j) t[tx*4 + j][it*16 + ty] = (_Float16)v[j];
  }
  __syncthreads();
  #pragma unroll
  for (int it = 0; it < 4; ++it) {
    int n = it*16 + ty;
    *(f16x4*)&d[(size_t)(n0 + n) * K + k0 + tx*4] = *(const f16x4*)&t[n][tx*4];
  }
}

// ---------------- GEMM1: act[p] = silu(hs@Wg) * (hs@Wu), f16 ----------------
// BM=128, BN=256, BK=32; wave tile 64x64 (g+u); 3 buffers, depth-2 counted vmcnt
#define G1_BUF 20480   // f16 per buffer: A 4096 | Bg 8192 | Bu 8192
__global__ __launch_bounds__(512) void k_gemm1(
    const _Float16* __restrict__ hs16, const _Float16* __restrict__ WgT,
    const _Float16* __restrict__ WuT, char* __restrict__ ws) {
  const int s = blockIdx.y;
  if (s >= *(const int*)(ws + WS_TOT)) return;
  const int e    = ((const int*)(ws + WS_TEXP))[s];
  const int m0   = ((const int*)(ws + WS_TM0))[s];
  const int offE = ((const int*)(ws + WS_OFF))[e];
  const int nE   = ((const int*)(ws + WS_CNT))[e];
  _Float16* __restrict__ act = (_Float16*)(ws + WS_ACT);
  const int n0 = blockIdx.x * 256;
  const int tid = threadIdx.x, lane = tid & 63, wid = tid >> 6;

  __shared__ __align__(16) _Float16 sm[3 * G1_BUF];   // 120 KB

  // staging lane map: 4 lanes/row, 16 rows per gll; source granule inverse-swizzled
  const int rL = lane >> 2;
  const int q  = (((lane & 3) ^ ((lane >> 3) & 3)) << 3);
  int tok;
  { int mm = m0 + 16*wid + rL;
    tok = (mm < nE) ? (((const int*)(ws + WS_PAIR))[offE + mm] >> 1) : 0; }
  const _Float16* aS  = hs16 + (size_t)tok * HD + q;
  const size_t cB0 = (size_t)e * ID + n0 + 32*wid + rL;
  const _Float16* gS0 = WgT + cB0 * HD + q;
  const _Float16* gS1 = gS0 + 16ull * HD;
  const _Float16* uS0 = WuT + cB0 * HD + q;
  const _Float16* uS1 = uS0 + 16ull * HD;

  auto stageAG = [&](int buf, int kt) {   // 3 gll: A + gate
    _Float16* b = sm + buf * G1_BUF;
    const int ko = kt * 32;
    gll16(aS  + ko, b + wid*512);
    gll16(gS0 + ko, b + 4096  + wid*1024);
    gll16(gS1 + ko, b + 4096  + wid*1024 + 512);
  };
  auto stageU = [&](int buf, int kt) {    // 2 gll: up
    _Float16* b = sm + buf * G1_BUF;
    const int ko = kt * 32;
    gll16(uS0 + ko, b + 12288 + wid*1024);
    gll16(uS1 + ko, b + 12288 + wid*1024 + 512);
  };

  const int wr = wid >> 2, wc = wid & 3;   // 2M x 4N waves, tile 64x64
  const int l15 = lane & 15, l4 = lane >> 4;
  f32x4 accg[4][4] = {}, accu[4][4] = {};

  auto compute = [&](int buf) {
    const _Float16* b0 = sm + buf * G1_BUF;
    f16x8 afr[4], bfr[4];
    #pragma unroll
    for (int i = 0; i < 4; ++i)
      afr[i] = *(const f16x8*)&b0[lofs(64*wr + 16*i + l15, l4)];
    #pragma unroll
    for (int j = 0; j < 4; ++j)
      bfr[j] = *(const f16x8*)&b0[4096 + lofs(64*wc + 16*j + l15, l4)];
    __builtin_amdgcn_s_setprio(1);
    #pragma unroll
    for (int i = 0; i < 4; ++i)
      #pragma unroll
      for (int j = 0; j < 4; ++j)
        accg[i][j] = __builtin_amdgcn_mfma_f32_16x16x32_f16(afr[i], bfr[j], accg[i][j], 0, 0, 0);
    __builtin_amdgcn_s_setprio(0);
    #pragma unroll
    for (int j = 0; j < 4; ++j)
      bfr[j] = *(const f16x8*)&b0[12288 + lofs(64*wc + 16*j + l15, l4)];
    __builtin_amdgcn_s_setprio(1);
    #pragma unroll
    for (int i = 0; i < 4; ++i)
      #pragma unroll
      for (int j = 0; j < 4; ++j)
        accu[i][j] = __builtin_amdgcn_mfma_f32_16x16x32_f16(afr[i], bfr[j], accu[i][j], 0, 0, 0);
    __builtin_amdgcn_s_setprio(0);
  };

  const int KT = HD / 32;                  // 32
  stageAG(0, 0); stageU(0, 0);
  stageAG(1, 1); stageU(1, 1);
  for (int t = 0; t < KT - 2; ++t) {
    const int nb = (t + 2) % 3;
    stageAG(nb, t + 2);                    // outstanding: t? + 5 + 3
    WAITV(8);                              // tile t fully landed
    __builtin_amdgcn_s_barrier();
    stageU(nb, t + 2);                     // rest of t+2 mid-phase
    compute(t % 3);
    __builtin_amdgcn_s_barrier();          // readers done before next restage
  }
  WAITV(5);
  __builtin_amdgcn_s_barrier();
  compute((KT - 2) % 3);
  __builtin_amdgcn_s_barrier();
  WAITV(0);
  __builtin_amdgcn_s_barrier();
  compute((KT - 1) % 3);

  #pragma unroll
  for (int i = 0; i < 4; ++i)
    #pragma unroll
    for (int r = 0; r < 4; ++r) {
      const int mm = m0 + 64*wr + 16*i + 4*l4 + r;   // C/D: col=lane&15, row=(lane>>4)*4+r
      if (mm < nE) {
        const size_t prow = (size_t)(offE + mm) * ID;
        #pragma unroll
        for (int j = 0; j < 4; ++j) {
          float g = accg[i][j][r], u = accu[i][j][r];
          float sv = g / (1.f + __expf(-g)) * u;
          act[prow + n0 + 64*wc + 16*j + l15] = (_Float16)sv;
        }
      }
    }
}

// ---------------- GEMM2: ybuf[id] = act[p] @ WdT[e] ----------------
// BM=256, BN=128, BK=32; wave tile 64x64; 3 buffers (72 KB), depth-2 vmcnt
#define G2_BUF 12288   // f16 per buffer: A 8192 | B 4096
__global__ __launch_bounds__(512) void k_gemm2(const _Float16* __restrict__ WdT,
                                               char* __restrict__ ws) {
  const int s = blockIdx.y;
  if (s >= *(const int*)(ws + WS_TOT2)) return;
  const int e    = ((const int*)(ws + WS_TEXP2))[s];
  const int m0   = ((const int*)(ws + WS_TM02))[s];
  const int offE = ((const int*)(ws + WS_OFF))[e];
  const int nE   = ((const int*)(ws + WS_CNT))[e];
  const int* __restrict__ pair = (const int*)(ws + WS_PAIR);
  const _Float16* __restrict__ act = (const _Float16*)(ws + WS_ACT);
  _Float16* __restrict__ ybuf = (_Float16*)(ws + WS_YBUF);
  const int n0 = blockIdx.x * 128;
  const int tid = threadIdx.x, lane = tid & 63, wid = tid >> 6;

  __shared__ __align__(16) _Float16 sm[3 * G2_BUF];   // 72 KB

  const int rL = lane >> 2;
  const int q  = (((lane & 3) ^ ((lane >> 3) & 3)) << 3);
  int pA0, pA1;
  { int mm = m0 + 32*wid + rL;       pA0 = (mm < nE) ? (offE + mm) : offE; }
  { int mm = m0 + 32*wid + 16 + rL;  pA1 = (mm < nE) ? (offE + mm) : offE; }
  const _Float16* aS0 = act + (size_t)pA0 * ID + q;
  const _Float16* aS1 = act + (size_t)pA1 * ID + q;
  const _Float16* bS  = WdT + ((size_t)e * HD + n0 + 16*wid + rL) * ID + q;

  auto stageBA = [&](int buf, int kt) {   // 2 gll: B + A-half0
    _Float16* b = sm + buf * G2_BUF;
    const int ko = kt * 32;
    gll16(bS  + ko, b + 8192 + wid*512);
    gll16(aS0 + ko, b + wid*1024);
  };
  auto stageA1 = [&](int buf, int kt) {   // 1 gll: A-half1
    _Float16* b = sm + buf * G2_BUF;
    gll16(aS1 + kt*32, b + wid*1024 + 512);
  };

  const int wr = wid >> 1, wc = wid & 1;   // 4M x 2N waves, tile 64x64
  const int l15 = lane & 15, l4 = lane >> 4;
  f32x4 acc[4][4] = {};

  auto compute = [&](int buf) {
    const _Float16* b0 = sm + buf * G2_BUF;
    f16x8 afr[4], bfr[4];
    #pragma unroll
    for (int i = 0; i < 4; ++i)
      afr[i] = *(const f16x8*)&b0[lofs(64*wr + 16*i + l15, l4)];
    #pragma unroll
    for (int j = 0; j < 4; ++j)
      bfr[j] = *(const f16x8*)&b0[8192 + lofs(64*wc + 16*j + l15, l4)];
    __builtin_amdgcn_s_setprio(1);
    #pragma unroll
    for (int i = 0; i < 4; ++i)
      #pragma unroll
      for (int j = 0; j < 4; ++j)
        acc[i][j] = __builtin_amdgcn_mfma_f32_16x16x32_f16(afr[i], bfr[j], acc[i][j], 0, 0, 0);
    __builtin_amdgcn_s_setprio(0);
  };

  const int KT = ID / 32;                  // 128
  stageBA(0, 0); stageA1(0, 0);
  stageBA(1, 1); stageA1(1, 1);
  for (int t = 0; t < KT - 2; ++t) {
    const int nb = (t + 2) % 3;
    stageBA(nb, t + 2);                    // outstanding: t? + 3 + 2
    WAITV(5);
    __builtin_amdgcn_s_barrier();
    stageA1(nb, t + 2);
    compute(t % 3);
    __builtin_amdgcn_s_barrier();
  }
  WAITV(3);
  __builtin_amdgcn_s_barrier();
  compute((KT - 2) % 3);
  __builtin_amdgcn_s_barrier();
  WAITV(0);
  __builtin_amdgcn_s_barrier();
  compute((KT - 1) % 3);

  #pragma unroll
  for (int i = 0; i < 4; ++i)
    #pragma unroll
    for (int r = 0; r < 4; ++r) {
      const int mm = m0 + 64*wr + 16*i + 4*l4 + r;
      if (mm < nE) {
        const int id = pair[offE + mm];
        #pragma unroll
        for (int j = 0; j < 4; ++j)
          ybuf[(size_t)id * HD + n0 + 64*wc + 16*j + l15] = (_Float16)acc[i][j][r];
      }
    }
}

// ---------------- combine ----------------
__global__ void k_combine(const char* __restrict__ ws, float* __restrict__ out) {
  const int idx = blockIdx.x * blockDim.x + threadIdx.x;   // over T*HD/8
  const int t = idx >> 7, c = idx & 127;
  const float* topw = (const float*)(ws + WS_TOPW);
  const _Float16* yb = (const _Float16*)(ws + WS_YBUF);
  f16x8 y0 = ((const f16x8*)(yb + (size_t)(2*t)     * HD))[c];
  f16x8 y1 = ((const f16x8*)(yb + (size_t)(2*t + 1) * HD))[c];
  const float w0 = topw[2*t], w1 = topw[2*t+1];
  f32x4 o0, o1;
  #pragma unroll
  for (int j = 0; j < 4; ++j) {
    o0[j] = w0 * (float)y0[j]     + w1 * (float)y1[j];
    o1[j] = w0 * (float)y0[4 + j] + w1 * (float)y1[4 + j];
  }
  ((f32x4*)out)[2*idx]     = o0;
  ((f32x4*)out)[2*idx + 1] = o1;
}

extern "C" void kernel_launch(void* const* d_in, const int* in_sizes, int n_in,
                              void* d_out, int out_size, void* d_ws, size_t ws_size,
                              hipStream_t stream) {
  const float* hs     = (const float*)d_in[0];
  const float* logits = (const float*)d_in[1];
  const float* Wg     = (const float*)d_in[2];
  const float* Wu     = (const float*)d_in[3];
  const float* Wd     = (const float*)d_in[4];
  char* ws = (char*)d_ws;   // requires ~295 MB of workspace

  _Float16* hs16 = (_Float16*)(ws + WS_HS16);
  _Float16* wg16 = (_Float16*)(ws + WS_WG16);
  _Float16* wu16 = (_Float16*)(ws + WS_WU16);
  _Float16* wd16 = (_Float16*)(ws + WS_WD16);

  hipMemsetAsync(ws, 0, 256, stream);
  k_router <<<dim3(T_TOK/256), dim3(256), 0, stream>>>(logits, ws);
  k_prefix <<<dim3(1),         dim3(64),  0, stream>>>(ws);
  k_scatter<<<dim3(T_TOK/256), dim3(256), 0, stream>>>(ws);
  k_hscvt  <<<dim3(T_TOK*HD/4/256), dim3(256), 0, stream>>>(hs, hs16);
  k_wtrans <<<dim3(ID/64, HD/64, NE), dim3(256), 0, stream>>>(Wg, wg16, HD, ID);
  k_wtrans <<<dim3(ID/64, HD/64, NE), dim3(256), 0, stream>>>(Wu, wu16, HD, ID);
  k_wtrans <<<dim3(HD/64, ID/64, NE), dim3(256), 0, stream>>>(Wd, wd16, ID, HD);
  k_gemm1  <<<dim3(ID/256, MAXT1), dim3(512), 0, stream>>>(hs16, wg16, wu16, ws);
  k_gemm2  <<<dim3(HD/128, MAXT2), dim3(512), 0, stream>>>(wd16, ws);
  k_combine<<<dim3(T_TOK*HD/8/256), dim3(256), 0, stream>>>(ws, (float*)d_out);
}

// Round 5
// 506.693 us; speedup vs baseline: 1.0527x; 1.0527x over previous
//
#include <hip/hip_runtime.h>

typedef float    f32x4 __attribute__((ext_vector_type(4)));
typedef _Float16 f16x8 __attribute__((ext_vector_type(8)));
typedef _Float16 f16x4 __attribute__((ext_vector_type(4)));

#define T_TOK 4096
#define HD    1024
#define ID    4096
#define NE    8
#define TOTP  (2*T_TOK)
#define MAXT1 72     // BM=128 tiles (gemm1)
#define MAXT2 40     // BM=256 tiles (gemm2)

// ---- workspace layout (bytes). Total ~295 MB ----
#define WS_CNT   0
#define WS_FILL  64
#define WS_OFF   128
#define WS_TOT   192
#define WS_TOT2  196
#define WS_TEXP  256
#define WS_TM0   (256 + 4*MAXT1)
#define WS_TEXP2 (256 + 8*MAXT1)
#define WS_TM02  (256 + 8*MAXT1 + 4*MAXT2)
#define WS_TOPE  2048
#define WS_TOPW  (WS_TOPE + 4*TOTP)
#define WS_PAIR  (WS_TOPW + 4*TOTP)
#define WS_ACT   ((size_t)1 << 20)                              // f16[TOTP*ID]   64 MB
constexpr size_t WS_YBUF = WS_ACT  + 2ull*TOTP*ID;              // f16[TOTP*HD]   16 MB
constexpr size_t WS_HS16 = WS_YBUF + 2ull*TOTP*HD;              // f16[T*HD]       8 MB
constexpr size_t WS_WG16 = WS_HS16 + 2ull*T_TOK*HD;             // f16[E][I][H]   67 MB
constexpr size_t WS_WU16 = WS_WG16 + 2ull*NE*HD*ID;             // f16[E][I][H]   67 MB
constexpr size_t WS_WD16 = WS_WU16 + 2ull*NE*HD*ID;             // f16[E][H][I]   67 MB

// async global->LDS, 16B per lane, wave-uniform LDS base
__device__ __forceinline__ void gll16(const void* g, void* l) {
  __builtin_amdgcn_global_load_lds(
      (const __attribute__((address_space(1))) unsigned int*)g,
      (__attribute__((address_space(3))) unsigned int*)l, 16, 0, 0);
}

#define WAITV(N) do { \
    asm volatile("s_waitcnt vmcnt(" #N ")" ::: "memory"); \
    __builtin_amdgcn_sched_barrier(0); \
  } while (0)

// [row][32] f16 tile: 16B-granule XOR swizzle (2-way bank aliasing = free)
__device__ __forceinline__ int lofs(int row, int g) {
  return row * 32 + ((g ^ ((row >> 1) & 3)) << 3);
}

// ---------------- routing ----------------
__global__ void k_router(const float* __restrict__ logits, char* __restrict__ ws) {
  int t = blockIdx.x * blockDim.x + threadIdx.x;
  if (t >= T_TOK) return;
  float v0 = -1e30f, v1 = -1e30f; int i0 = 0, i1 = 0;
  #pragma unroll
  for (int e = 0; e < NE; ++e) {
    float v = logits[t * NE + e];
    if (v > v0)      { v1 = v0; i1 = i0; v0 = v; i0 = e; }
    else if (v > v1) { v1 = v;  i1 = e; }
  }
  float w0 = 1.f / (1.f + __expf(v1 - v0));
  ((int*)(ws + WS_TOPE))[2*t]   = i0;
  ((int*)(ws + WS_TOPE))[2*t+1] = i1;
  ((float*)(ws + WS_TOPW))[2*t]   = w0;
  ((float*)(ws + WS_TOPW))[2*t+1] = 1.f - w0;
  atomicAdd(&((int*)(ws + WS_CNT))[i0], 1);
  atomicAdd(&((int*)(ws + WS_CNT))[i1], 1);
}

__global__ void k_prefix(char* __restrict__ ws) {
  if (threadIdx.x != 0 || blockIdx.x != 0) return;
  const int* cnt = (const int*)(ws + WS_CNT);
  int* off   = (int*)(ws + WS_OFF);
  int* texp  = (int*)(ws + WS_TEXP);
  int* tm0   = (int*)(ws + WS_TM0);
  int* texp2 = (int*)(ws + WS_TEXP2);
  int* tm02  = (int*)(ws + WS_TM02);
  int run = 0, t1 = 0, t2 = 0;
  for (int e = 0; e < NE; ++e) {
    off[e] = run;
    int ne = cnt[e];
    for (int i = 0; i < ne; i += 128) { texp[t1] = e; tm0[t1] = i; ++t1; }
    for (int i = 0; i < ne; i += 256) { texp2[t2] = e; tm02[t2] = i; ++t2; }
    run += ne;
  }
  off[NE] = run;
  *(int*)(ws + WS_TOT)  = t1;
  *(int*)(ws + WS_TOT2) = t2;
}

__global__ void k_scatter(char* __restrict__ ws) {
  int t = blockIdx.x * blockDim.x + threadIdx.x;
  if (t >= T_TOK) return;
  const int* tope = (const int*)(ws + WS_TOPE);
  const int* off  = (const int*)(ws + WS_OFF);
  int* fill = (int*)(ws + WS_FILL);
  int* pair = (int*)(ws + WS_PAIR);
  #pragma unroll
  for (int s = 0; s < 2; ++s) {
    int id = 2*t + s;
    int e = tope[id];
    int pos = off[e] + atomicAdd(&fill[e], 1);
    pair[pos] = id;   // order nondeterministic; ybuf row = id keeps output deterministic
  }
}

// ---------------- conversions ----------------
__global__ void k_hscvt(const float* __restrict__ src, _Float16* __restrict__ dst) {
  int i = blockIdx.x * blockDim.x + threadIdx.x;
  f32x4 v = ((const f32x4*)src)[i];
  f16x4 o;
  #pragma unroll
  for (int j = 0; j < 4; ++j) o[j] = (_Float16)v[j];
  ((f16x4*)dst)[i] = o;
}

// f32 [e][K][N] -> f16 [e][N][K], 64x64 tiles via LDS
__global__ __launch_bounds__(256) void k_wtrans(const float* __restrict__ src,
                                                _Float16* __restrict__ dst,
                                                int K, int N) {
  const int e = blockIdx.z;
  const int n0 = blockIdx.x * 64, k0 = blockIdx.y * 64;
  const float* s = src + (size_t)e * K * N;
  _Float16* d = dst + (size_t)e * (size_t)K * N;
  __shared__ _Float16 t[64][68];
  const int tx = threadIdx.x & 15, ty = threadIdx.x >> 4;
  #pragma unroll
  for (int it = 0; it < 4; ++it) {
    int k = k0 + it*16 + ty;
    f32x4 v = *(const f32x4*)&s[(size_t)k * N + n0 + tx*4];
    #pragma unroll
    for (int j = 0; j < 4; ++j) t[tx*4 + j][it*16 + ty] = (_Float16)v[j];
  }
  __syncthreads();
  #pragma unroll
  for (int it = 0; it < 4; ++it) {
    int n = it*16 + ty;
    *(f16x4*)&d[(size_t)(n0 + n) * K + k0 + tx*4] = *(const f16x4*)&t[n][tx*4];
  }
}

// ---------------- GEMM1: act[p] = silu(hs@Wg) * (hs@Wu), f16 ----------------
// BM=128, BN=128, BK=32; 4 waves (2x2), wave tile 64x64 dual-B; 3 bufs = 72 KB
#define G1_BUF 12288   // f16/buffer: A 4096 | Bg 4096 | Bu 4096
__global__ __launch_bounds__(256, 2) void k_gemm1(
    const _Float16* __restrict__ hs16, const _Float16* __restrict__ WgT,
    const _Float16* __restrict__ WuT, char* __restrict__ ws) {
  const int s = blockIdx.y;
  if (s >= *(const int*)(ws + WS_TOT)) return;
  const int e    = ((const int*)(ws + WS_TEXP))[s];
  const int m0   = ((const int*)(ws + WS_TM0))[s];
  const int offE = ((const int*)(ws + WS_OFF))[e];
  const int nE   = ((const int*)(ws + WS_CNT))[e];
  _Float16* __restrict__ act = (_Float16*)(ws + WS_ACT);
  const int n0 = blockIdx.x * 128;
  const int tid = threadIdx.x, lane = tid & 63, wid = tid >> 6;

  __shared__ __align__(16) _Float16 sm[3 * G1_BUF];   // 72 KB

  // staging lane map: row = 16-aligned base + (lane>>2); source granule
  // inverse-swizzled (rule 21: linear LDS dest + pre-swizzled global src)
  const int rL = lane >> 2;
  const int q  = (((lane & 3) ^ ((lane >> 3) & 3)) << 3);
  const _Float16 *aS[2], *gS[2], *uS[2];
  #pragma unroll
  for (int j = 0; j < 2; ++j) {
    int mm = m0 + 32*wid + 16*j + rL;
    int tok = (mm < nE) ? (((const int*)(ws + WS_PAIR))[offE + mm] >> 1) : 0;
    aS[j] = hs16 + (size_t)tok * HD + q;
    size_t cB = (size_t)e * ID + (n0 + 32*wid + 16*j + rL);
    gS[j] = WgT + cB * HD + q;
    uS[j] = WuT + cB * HD + q;
  }

  auto stage = [&](int buf, int kt) {   // 6 gll per wave per tile
    _Float16* b = sm + buf * G1_BUF + wid*1024;
    const int ko = kt * 32;
    #pragma unroll
    for (int j = 0; j < 2; ++j) {
      gll16(aS[j] + ko, b + j*512);
      gll16(gS[j] + ko, b + 4096 + j*512);
      gll16(uS[j] + ko, b + 8192 + j*512);
    }
  };

  const int wr = wid >> 1, wc = wid & 1;   // 2M x 2N waves, tile 64x64
  const int l15 = lane & 15, l4 = lane >> 4;
  f32x4 accg[4][4] = {}, accu[4][4] = {};

  auto compute = [&](int buf) {
    const _Float16* b0 = sm + buf * G1_BUF;
    f16x8 afr[4], bfr[4];
    #pragma unroll
    for (int i = 0; i < 4; ++i)
      afr[i] = *(const f16x8*)&b0[lofs(64*wr + 16*i + l15, l4)];
    #pragma unroll
    for (int j = 0; j < 4; ++j)
      bfr[j] = *(const f16x8*)&b0[4096 + lofs(64*wc + 16*j + l15, l4)];
    __builtin_amdgcn_s_setprio(1);
    #pragma unroll
    for (int i = 0; i < 4; ++i)
      #pragma unroll
      for (int j = 0; j < 4; ++j)
        accg[i][j] = __builtin_amdgcn_mfma_f32_16x16x32_f16(afr[i], bfr[j], accg[i][j], 0, 0, 0);
    __builtin_amdgcn_s_setprio(0);
    #pragma unroll
    for (int j = 0; j < 4; ++j)
      bfr[j] = *(const f16x8*)&b0[8192 + lofs(64*wc + 16*j + l15, l4)];
    __builtin_amdgcn_s_setprio(1);
    #pragma unroll
    for (int i = 0; i < 4; ++i)
      #pragma unroll
      for (int j = 0; j < 4; ++j)
        accu[i][j] = __builtin_amdgcn_mfma_f32_16x16x32_f16(afr[i], bfr[j], accu[i][j], 0, 0, 0);
    __builtin_amdgcn_s_setprio(0);
  };

  auto step = [&](int t, int cur, int nb) {
    stage(nb, t + 2);
    WAITV(12);                             // tile t landed; t+1,t+2 in flight
    __builtin_amdgcn_s_barrier();
    compute(cur);
    __builtin_amdgcn_s_barrier();          // readers done before next restage
  };

  const int KT = HD / 32;                  // 32; KT-2 = 30 = 3*10
  stage(0, 0); stage(1, 1);
  for (int t = 0; t < KT - 2; t += 3) {    // static buffer indices
    step(t,     0, 2);
    step(t + 1, 1, 0);
    step(t + 2, 2, 1);
  }
  WAITV(6);
  __builtin_amdgcn_s_barrier();
  compute(0);                              // tile KT-2 (30%3==0)
  __builtin_amdgcn_s_barrier();
  WAITV(0);
  __builtin_amdgcn_s_barrier();
  compute(1);                              // tile KT-1

  #pragma unroll
  for (int i = 0; i < 4; ++i)
    #pragma unroll
    for (int r = 0; r < 4; ++r) {
      const int mm = m0 + 64*wr + 16*i + 4*l4 + r;   // C/D: col=lane&15, row=(lane>>4)*4+r
      if (mm < nE) {
        const size_t prow = (size_t)(offE + mm) * ID;
        #pragma unroll
        for (int j = 0; j < 4; ++j) {
          float g = accg[i][j][r], u = accu[i][j][r];
          float sv = g / (1.f + __expf(-g)) * u;
          act[prow + n0 + 64*wc + 16*j + l15] = (_Float16)sv;
        }
      }
    }
}

// ---------------- GEMM2: ybuf[id] = act[p] @ WdT[e] ----------------
// BM=256, BN=128, BK=32; 4 waves (2x2), wave tile 128x64; 3 bufs = 72 KB
#define G2_BUF 12288   // f16/buffer: A 8192 | B 4096
__global__ __launch_bounds__(256, 2) void k_gemm2(const _Float16* __restrict__ WdT,
                                                  char* __restrict__ ws) {
  const int s = blockIdx.y;
  if (s >= *(const int*)(ws + WS_TOT2)) return;
  const int e    = ((const int*)(ws + WS_TEXP2))[s];
  const int m0   = ((const int*)(ws + WS_TM02))[s];
  const int offE = ((const int*)(ws + WS_OFF))[e];
  const int nE   = ((const int*)(ws + WS_CNT))[e];
  const int* __restrict__ pair = (const int*)(ws + WS_PAIR);
  const _Float16* __restrict__ act = (const _Float16*)(ws + WS_ACT);
  _Float16* __restrict__ ybuf = (_Float16*)(ws + WS_YBUF);
  const int n0 = blockIdx.x * 128;
  const int tid = threadIdx.x, lane = tid & 63, wid = tid >> 6;

  __shared__ __align__(16) _Float16 sm[3 * G2_BUF];   // 72 KB

  const int rL = lane >> 2;
  const int q  = (((lane & 3) ^ ((lane >> 3) & 3)) << 3);
  const _Float16 *aS[4], *bS[2];
  #pragma unroll
  for (int j = 0; j < 4; ++j) {          // A: wave w stages rows 64w..64w+63
    int mm = m0 + 64*wid + 16*j + rL;
    int p = (mm < nE) ? (offE + mm) : offE;
    aS[j] = act + (size_t)p * ID + q;
  }
  #pragma unroll
  for (int j = 0; j < 2; ++j)            // B: wave w stages cols 32w..32w+31
    bS[j] = WdT + ((size_t)e * HD + (n0 + 32*wid + 16*j + rL)) * ID + q;

  auto stage = [&](int buf, int kt) {    // 6 gll per wave per tile
    _Float16* b = sm + buf * G2_BUF;
    const int ko = kt * 32;
    #pragma unroll
    for (int j = 0; j < 4; ++j) gll16(aS[j] + ko, b + wid*2048 + j*512);
    #pragma unroll
    for (int j = 0; j < 2; ++j) gll16(bS[j] + ko, b + 8192 + wid*1024 + j*512);
  };

  const int wr = wid >> 1, wc = wid & 1;   // 2M x 2N waves, tile 128x64
  const int l15 = lane & 15, l4 = lane >> 4;
  f32x4 acc[8][4] = {};

  auto compute = [&](int buf) {
    const _Float16* b0 = sm + buf * G2_BUF;
    f16x8 afr[8], bfr[4];
    #pragma unroll
    for (int i = 0; i < 8; ++i)
      afr[i] = *(const f16x8*)&b0[lofs(128*wr + 16*i + l15, l4)];
    #pragma unroll
    for (int j = 0; j < 4; ++j)
      bfr[j] = *(const f16x8*)&b0[8192 + lofs(64*wc + 16*j + l15, l4)];
    __builtin_amdgcn_s_setprio(1);
    #pragma unroll
    for (int i = 0; i < 8; ++i)
      #pragma unroll
      for (int j = 0; j < 4; ++j)
        acc[i][j] = __builtin_amdgcn_mfma_f32_16x16x32_f16(afr[i], bfr[j], acc[i][j], 0, 0, 0);
    __builtin_amdgcn_s_setprio(0);
  };

  auto step = [&](int t, int cur, int nb) {
    stage(nb, t + 2);
    WAITV(12);
    __builtin_amdgcn_s_barrier();
    compute(cur);
    __builtin_amdgcn_s_barrier();
  };

  const int KT = ID / 32;                  // 128; KT-2 = 126 = 3*42
  stage(0, 0); stage(1, 1);
  for (int t = 0; t < KT - 2; t += 3) {
    step(t,     0, 2);
    step(t + 1, 1, 0);
    step(t + 2, 2, 1);
  }
  WAITV(6);
  __builtin_amdgcn_s_barrier();
  compute(0);                              // tile 126
  __builtin_amdgcn_s_barrier();
  WAITV(0);
  __builtin_amdgcn_s_barrier();
  compute(1);                              // tile 127

  #pragma unroll
  for (int i = 0; i < 8; ++i)
    #pragma unroll
    for (int r = 0; r < 4; ++r) {
      const int mm = m0 + 128*wr + 16*i + 4*l4 + r;
      if (mm < nE) {
        const int id = pair[offE + mm];
        #pragma unroll
        for (int j = 0; j < 4; ++j)
          ybuf[(size_t)id * HD + n0 + 64*wc + 16*j + l15] = (_Float16)acc[i][j][r];
      }
    }
}

// ---------------- combine ----------------
__global__ void k_combine(const char* __restrict__ ws, float* __restrict__ out) {
  const int idx = blockIdx.x * blockDim.x + threadIdx.x;   // over T*HD/8
  const int t = idx >> 7, c = idx & 127;
  const float* topw = (const float*)(ws + WS_TOPW);
  const _Float16* yb = (const _Float16*)(ws + WS_YBUF);
  f16x8 y0 = ((const f16x8*)(yb + (size_t)(2*t)     * HD))[c];
  f16x8 y1 = ((const f16x8*)(yb + (size_t)(2*t + 1) * HD))[c];
  const float w0 = topw[2*t], w1 = topw[2*t+1];
  f32x4 o0, o1;
  #pragma unroll
  for (int j = 0; j < 4; ++j) {
    o0[j] = w0 * (float)y0[j]     + w1 * (float)y1[j];
    o1[j] = w0 * (float)y0[4 + j] + w1 * (float)y1[4 + j];
  }
  ((f32x4*)out)[2*idx]     = o0;
  ((f32x4*)out)[2*idx + 1] = o1;
}

extern "C" void kernel_launch(void* const* d_in, const int* in_sizes, int n_in,
                              void* d_out, int out_size, void* d_ws, size_t ws_size,
                              hipStream_t stream) {
  const float* hs     = (const float*)d_in[0];
  const float* logits = (const float*)d_in[1];
  const float* Wg     = (const float*)d_in[2];
  const float* Wu     = (const float*)d_in[3];
  const float* Wd     = (const float*)d_in[4];
  char* ws = (char*)d_ws;   // requires ~295 MB of workspace

  _Float16* hs16 = (_Float16*)(ws + WS_HS16);
  _Float16* wg16 = (_Float16*)(ws + WS_WG16);
  _Float16* wu16 = (_Float16*)(ws + WS_WU16);
  _Float16* wd16 = (_Float16*)(ws + WS_WD16);

  hipMemsetAsync(ws, 0, 256, stream);
  k_router <<<dim3(T_TOK/256), dim3(256), 0, stream>>>(logits, ws);
  k_prefix <<<dim3(1),         dim3(64),  0, stream>>>(ws);
  k_scatter<<<dim3(T_TOK/256), dim3(256), 0, stream>>>(ws);
  k_hscvt  <<<dim3(T_TOK*HD/4/256), dim3(256), 0, stream>>>(hs, hs16);
  k_wtrans <<<dim3(ID/64, HD/64, NE), dim3(256), 0, stream>>>(Wg, wg16, HD, ID);
  k_wtrans <<<dim3(ID/64, HD/64, NE), dim3(256), 0, stream>>>(Wu, wu16, HD, ID);
  k_wtrans <<<dim3(HD/64, ID/64, NE), dim3(256), 0, stream>>>(Wd, wd16, ID, HD);
  k_gemm1  <<<dim3(ID/128, MAXT1), dim3(256), 0, stream>>>(hs16, wg16, wu16, ws);
  k_gemm2  <<<dim3(HD/128, MAXT2), dim3(256), 0, stream>>>(wd16, ws);
  k_combine<<<dim3(T_TOK*HD/8/256), dim3(256), 0, stream>>>(ws, (float*)d_out);
}

// Round 6
// 501.077 us; speedup vs baseline: 1.0645x; 1.0112x over previous
//
#include <hip/hip_runtime.h>

typedef float    f32x4 __attribute__((ext_vector_type(4)));
typedef _Float16 f16x8 __attribute__((ext_vector_type(8)));
typedef _Float16 f16x4 __attribute__((ext_vector_type(4)));

#define T_TOK 4096
#define HD    1024
#define ID    4096
#define NE    8
#define TOTP  (2*T_TOK)
#define MAXT1 72     // BM=128 tiles (unused by gemms now, kept in prefix)
#define MAXT2 40     // BM=256 tiles (gemm1 + gemm2)

// ---- workspace layout (bytes). Total ~295 MB ----
#define WS_CNT   0
#define WS_FILL  64
#define WS_OFF   128
#define WS_TOT   192
#define WS_TOT2  196
#define WS_TEXP  256
#define WS_TM0   (256 + 4*MAXT1)
#define WS_TEXP2 (256 + 8*MAXT1)
#define WS_TM02  (256 + 8*MAXT1 + 4*MAXT2)
#define WS_TOPE  2048
#define WS_TOPW  (WS_TOPE + 4*TOTP)
#define WS_PAIR  (WS_TOPW + 4*TOTP)
#define WS_ACT   ((size_t)1 << 20)                              // f16[TOTP*ID]   64 MB
constexpr size_t WS_YBUF = WS_ACT  + 2ull*TOTP*ID;              // f16[TOTP*HD]   16 MB
constexpr size_t WS_HS16 = WS_YBUF + 2ull*TOTP*HD;              // f16[T*HD]       8 MB
constexpr size_t WS_WG16 = WS_HS16 + 2ull*T_TOK*HD;             // f16[E][I][H]   67 MB
constexpr size_t WS_WU16 = WS_WG16 + 2ull*NE*HD*ID;             // f16[E][I][H]   67 MB
constexpr size_t WS_WD16 = WS_WU16 + 2ull*NE*HD*ID;             // f16[E][H][I]   67 MB

// async global->LDS, 16B per lane, wave-uniform LDS base
__device__ __forceinline__ void gll16(const void* g, void* l) {
  __builtin_amdgcn_global_load_lds(
      (const __attribute__((address_space(1))) unsigned int*)g,
      (__attribute__((address_space(3))) unsigned int*)l, 16, 0, 0);
}

#define WAITV(N) do { \
    asm volatile("s_waitcnt vmcnt(" #N ")" ::: "memory"); \
    __builtin_amdgcn_sched_barrier(0); \
  } while (0)

// [row][32] f16 tile swizzle (BK=32 path, gemm2)
__device__ __forceinline__ int lofs(int row, int g) {
  return row * 32 + ((g ^ ((row >> 1) & 3)) << 3);
}
// [row][64] f16 tile swizzle (BK=64 path, gemm1): 8 granules XOR row&7
__device__ __forceinline__ int lofs64(int row, int g8) {
  return row * 64 + ((g8 ^ (row & 7)) << 3);
}

// ---------------- routing ----------------
__global__ void k_router(const float* __restrict__ logits, char* __restrict__ ws) {
  int t = blockIdx.x * blockDim.x + threadIdx.x;
  if (t >= T_TOK) return;
  float v0 = -1e30f, v1 = -1e30f; int i0 = 0, i1 = 0;
  #pragma unroll
  for (int e = 0; e < NE; ++e) {
    float v = logits[t * NE + e];
    if (v > v0)      { v1 = v0; i1 = i0; v0 = v; i0 = e; }
    else if (v > v1) { v1 = v;  i1 = e; }
  }
  float w0 = 1.f / (1.f + __expf(v1 - v0));
  ((int*)(ws + WS_TOPE))[2*t]   = i0;
  ((int*)(ws + WS_TOPE))[2*t+1] = i1;
  ((float*)(ws + WS_TOPW))[2*t]   = w0;
  ((float*)(ws + WS_TOPW))[2*t+1] = 1.f - w0;
  atomicAdd(&((int*)(ws + WS_CNT))[i0], 1);
  atomicAdd(&((int*)(ws + WS_CNT))[i1], 1);
}

__global__ void k_prefix(char* __restrict__ ws) {
  if (threadIdx.x != 0 || blockIdx.x != 0) return;
  const int* cnt = (const int*)(ws + WS_CNT);
  int* off   = (int*)(ws + WS_OFF);
  int* texp  = (int*)(ws + WS_TEXP);
  int* tm0   = (int*)(ws + WS_TM0);
  int* texp2 = (int*)(ws + WS_TEXP2);
  int* tm02  = (int*)(ws + WS_TM02);
  int run = 0, t1 = 0, t2 = 0;
  for (int e = 0; e < NE; ++e) {
    off[e] = run;
    int ne = cnt[e];
    for (int i = 0; i < ne; i += 128) { texp[t1] = e; tm0[t1] = i; ++t1; }
    for (int i = 0; i < ne; i += 256) { texp2[t2] = e; tm02[t2] = i; ++t2; }
    run += ne;
  }
  off[NE] = run;
  *(int*)(ws + WS_TOT)  = t1;
  *(int*)(ws + WS_TOT2) = t2;
}

__global__ void k_scatter(char* __restrict__ ws) {
  int t = blockIdx.x * blockDim.x + threadIdx.x;
  if (t >= T_TOK) return;
  const int* tope = (const int*)(ws + WS_TOPE);
  const int* off  = (const int*)(ws + WS_OFF);
  int* fill = (int*)(ws + WS_FILL);
  int* pair = (int*)(ws + WS_PAIR);
  #pragma unroll
  for (int s = 0; s < 2; ++s) {
    int id = 2*t + s;
    int e = tope[id];
    int pos = off[e] + atomicAdd(&fill[e], 1);
    pair[pos] = id;   // order nondeterministic; ybuf row = id keeps output deterministic
  }
}

// ---------------- conversions ----------------
__global__ void k_hscvt(const float* __restrict__ src, _Float16* __restrict__ dst) {
  int i = blockIdx.x * blockDim.x + threadIdx.x;
  f32x4 v = ((const f32x4*)src)[i];
  f16x4 o;
  #pragma unroll
  for (int j = 0; j < 4; ++j) o[j] = (_Float16)v[j];
  ((f16x4*)dst)[i] = o;
}

// f32 [e][K][N] -> f16 [e][N][K], 64x64 tiles via LDS
__global__ __launch_bounds__(256) void k_wtrans(const float* __restrict__ src,
                                                _Float16* __restrict__ dst,
                                                int K, int N) {
  const int e = blockIdx.z;
  const int n0 = blockIdx.x * 64, k0 = blockIdx.y * 64;
  const float* s = src + (size_t)e * K * N;
  _Float16* d = dst + (size_t)e * (size_t)K * N;
  __shared__ _Float16 t[64][68];
  const int tx = threadIdx.x & 15, ty = threadIdx.x >> 4;
  #pragma unroll
  for (int it = 0; it < 4; ++it) {
    int k = k0 + it*16 + ty;
    f32x4 v = *(const f32x4*)&s[(size_t)k * N + n0 + tx*4];
    #pragma unroll
    for (int j = 0; j < 4; ++j) t[tx*4 + j][it*16 + ty] = (_Float16)v[j];
  }
  __syncthreads();
  #pragma unroll
  for (int it = 0; it < 4; ++it) {
    int n = it*16 + ty;
    *(f16x4*)&d[(size_t)(n0 + n) * K + k0 + tx*4] = *(const f16x4*)&t[n][tx*4];
  }
}

// ---------------- GEMM1: act[p] = silu(hs@Wg) * (hs@Wu), f16 ----------------
// BM=256, BN=128 dual-B, BK=64; 8 waves (2M x 4N), wave tile 128x32 for g AND u.
// 1 block/CU, 128 KB dbuf LDS, 1 barrier + 1 vmcnt drain per K-tile.
__global__ __launch_bounds__(512, 2) void k_gemm1(
    const _Float16* __restrict__ hs16, const _Float16* __restrict__ WgT,
    const _Float16* __restrict__ WuT, char* __restrict__ ws) {
  const int s = blockIdx.y;
  if (s >= *(const int*)(ws + WS_TOT2)) return;
  const int e    = ((const int*)(ws + WS_TEXP2))[s];
  const int m0   = ((const int*)(ws + WS_TM02))[s];
  const int offE = ((const int*)(ws + WS_OFF))[e];
  const int nE   = ((const int*)(ws + WS_CNT))[e];
  _Float16* __restrict__ act = (_Float16*)(ws + WS_ACT);
  const int n0 = blockIdx.x * 128;
  const int tid = threadIdx.x, lane = tid & 63, wid = tid >> 6;

  // per buffer (f16 idx): A[256][64] @0 | Bg[128][64] @16384 | Bu[128][64] @24576
  __shared__ __align__(16) _Float16 sm[2 * 32768];   // 128 KB

  // staging lane map: 8 lanes/row, 8 rows/gll; base rows 8-aligned =>
  // inverse-swizzled source granule q64 = ((lane&7) ^ (lane>>3)) * 8
  const int r8 = lane >> 3;
  const int q64 = (((lane & 7) ^ r8) << 3);
  const int* __restrict__ pairp = (const int*)(ws + WS_PAIR);
  const _Float16 *aP[4], *gP[2], *uP[2];
  #pragma unroll
  for (int c = 0; c < 4; ++c) {        // A: wave stages rows 32w..32w+31
    int mm = m0 + 32*wid + 8*c + r8;
    int tok = (mm < nE) ? (pairp[offE + mm] >> 1) : 0;
    aP[c] = hs16 + (size_t)tok * HD + q64;
  }
  #pragma unroll
  for (int c = 0; c < 2; ++c) {        // B: wave stages cols 16w..16w+15
    size_t col = (size_t)e * ID + (n0 + 16*wid + 8*c + r8);
    gP[c] = WgT + col * HD + q64;
    uP[c] = WuT + col * HD + q64;
  }

  auto stage8 = [&](int buf, int kt) {   // 8 gll per wave per K-tile
    _Float16* base = sm + buf * 32768;
    const int ko = kt * 64;
    #pragma unroll
    for (int c = 0; c < 4; ++c)
      gll16(aP[c] + ko, base + (32*wid + 8*c) * 64);
    #pragma unroll
    for (int c = 0; c < 2; ++c) {
      gll16(gP[c] + ko, base + 16384 + (16*wid + 8*c) * 64);
      gll16(uP[c] + ko, base + 24576 + (16*wid + 8*c) * 64);
    }
  };

  const int wr = wid >> 2, wc = wid & 3;   // 2M x 4N
  const int l15 = lane & 15, l4 = lane >> 4;
  f32x4 accg[8][2] = {}, accu[8][2] = {};

  auto computeKK = [&](int buf, int kk) {  // one K=32 half: 12 reads, 32 MFMA
    const _Float16* b0 = sm + buf * 32768;
    f16x8 afr[8], bg[2], bu[2];
    #pragma unroll
    for (int i = 0; i < 8; ++i) {
      const int row = 128*wr + 16*i + l15;
      afr[i] = *(const f16x8*)&b0[lofs64(row, kk*4 + l4)];
    }
    #pragma unroll
    for (int j = 0; j < 2; ++j) {
      const int row = 32*wc + 16*j + l15;
      bg[j] = *(const f16x8*)&b0[16384 + lofs64(row, kk*4 + l4)];
      bu[j] = *(const f16x8*)&b0[24576 + lofs64(row, kk*4 + l4)];
    }
    __builtin_amdgcn_s_setprio(1);
    #pragma unroll
    for (int i = 0; i < 8; ++i)
      #pragma unroll
      for (int j = 0; j < 2; ++j) {
        accg[i][j] = __builtin_amdgcn_mfma_f32_16x16x32_f16(afr[i], bg[j], accg[i][j], 0, 0, 0);
        accu[i][j] = __builtin_amdgcn_mfma_f32_16x16x32_f16(afr[i], bu[j], accu[i][j], 0, 0, 0);
      }
    __builtin_amdgcn_s_setprio(0);
  };

  const int KT = HD / 64;                  // 16
  stage8(0, 0);
  WAITV(0);
  __builtin_amdgcn_s_barrier();
  for (int t = 0; t < KT; ++t) {
    const int cur = t & 1;
    if (t + 1 < KT) stage8(cur ^ 1, t + 1);  // issue early; retires under MFMA
    computeKK(cur, 0);
    computeKK(cur, 1);
    WAITV(0);                                // next tile fully landed
    __builtin_amdgcn_s_barrier();            // + everyone done reading cur
  }

  #pragma unroll
  for (int i = 0; i < 8; ++i)
    #pragma unroll
    for (int r = 0; r < 4; ++r) {
      const int mm = m0 + 128*wr + 16*i + 4*l4 + r;   // C/D: col=lane&15, row=(lane>>4)*4+r
      if (mm < nE) {
        const size_t prow = (size_t)(offE + mm) * ID;
        #pragma unroll
        for (int j = 0; j < 2; ++j) {
          float g = accg[i][j][r], u = accu[i][j][r];
          float sv = g / (1.f + __expf(-g)) * u;
          act[prow + n0 + 32*wc + 16*j + l15] = (_Float16)sv;
        }
      }
    }
}

// ---------------- GEMM2: ybuf[id] = act[p] @ WdT[e] ----------------
// BM=256, BN=128, BK=32; 4 waves (2x2), wave tile 128x64; 3 bufs = 72 KB
#define G2_BUF 12288   // f16/buffer: A 8192 | B 4096
__global__ __launch_bounds__(256, 2) void k_gemm2(const _Float16* __restrict__ WdT,
                                                  char* __restrict__ ws) {
  const int s = blockIdx.y;
  if (s >= *(const int*)(ws + WS_TOT2)) return;
  const int e    = ((const int*)(ws + WS_TEXP2))[s];
  const int m0   = ((const int*)(ws + WS_TM02))[s];
  const int offE = ((const int*)(ws + WS_OFF))[e];
  const int nE   = ((const int*)(ws + WS_CNT))[e];
  const int* __restrict__ pair = (const int*)(ws + WS_PAIR);
  const _Float16* __restrict__ act = (const _Float16*)(ws + WS_ACT);
  _Float16* __restrict__ ybuf = (_Float16*)(ws + WS_YBUF);
  const int n0 = blockIdx.x * 128;
  const int tid = threadIdx.x, lane = tid & 63, wid = tid >> 6;

  __shared__ __align__(16) _Float16 sm[3 * G2_BUF];   // 72 KB

  const int rL = lane >> 2;
  const int q  = (((lane & 3) ^ ((lane >> 3) & 3)) << 3);
  const _Float16 *aS[4], *bS[2];
  #pragma unroll
  for (int j = 0; j < 4; ++j) {          // A: wave w stages rows 64w..64w+63
    int mm = m0 + 64*wid + 16*j + rL;
    int p = (mm < nE) ? (offE + mm) : offE;
    aS[j] = act + (size_t)p * ID + q;
  }
  #pragma unroll
  for (int j = 0; j < 2; ++j)            // B: wave w stages cols 32w..32w+31
    bS[j] = WdT + ((size_t)e * HD + (n0 + 32*wid + 16*j + rL)) * ID + q;

  auto stage = [&](int buf, int kt) {    // 6 gll per wave per tile
    _Float16* b = sm + buf * G2_BUF;
    const int ko = kt * 32;
    #pragma unroll
    for (int j = 0; j < 4; ++j) gll16(aS[j] + ko, b + wid*2048 + j*512);
    #pragma unroll
    for (int j = 0; j < 2; ++j) gll16(bS[j] + ko, b + 8192 + wid*1024 + j*512);
  };

  const int wr = wid >> 1, wc = wid & 1;   // 2M x 2N waves, tile 128x64
  const int l15 = lane & 15, l4 = lane >> 4;
  f32x4 acc[8][4] = {};

  auto compute = [&](int buf) {
    const _Float16* b0 = sm + buf * G2_BUF;
    f16x8 afr[8], bfr[4];
    #pragma unroll
    for (int i = 0; i < 8; ++i)
      afr[i] = *(const f16x8*)&b0[lofs(128*wr + 16*i + l15, l4)];
    #pragma unroll
    for (int j = 0; j < 4; ++j)
      bfr[j] = *(const f16x8*)&b0[8192 + lofs(64*wc + 16*j + l15, l4)];
    __builtin_amdgcn_s_setprio(1);
    #pragma unroll
    for (int i = 0; i < 8; ++i)
      #pragma unroll
      for (int j = 0; j < 4; ++j)
        acc[i][j] = __builtin_amdgcn_mfma_f32_16x16x32_f16(afr[i], bfr[j], acc[i][j], 0, 0, 0);
    __builtin_amdgcn_s_setprio(0);
  };

  auto step = [&](int t, int cur, int nb) {
    stage(nb, t + 2);
    WAITV(12);
    __builtin_amdgcn_s_barrier();
    compute(cur);
    __builtin_amdgcn_s_barrier();
  };

  const int KT = ID / 32;                  // 128; KT-2 = 126 = 3*42
  stage(0, 0); stage(1, 1);
  for (int t = 0; t < KT - 2; t += 3) {
    step(t,     0, 2);
    step(t + 1, 1, 0);
    step(t + 2, 2, 1);
  }
  WAITV(6);
  __builtin_amdgcn_s_barrier();
  compute(0);                              // tile 126
  __builtin_amdgcn_s_barrier();
  WAITV(0);
  __builtin_amdgcn_s_barrier();
  compute(1);                              // tile 127

  #pragma unroll
  for (int i = 0; i < 8; ++i)
    #pragma unroll
    for (int r = 0; r < 4; ++r) {
      const int mm = m0 + 128*wr + 16*i + 4*l4 + r;
      if (mm < nE) {
        const int id = pair[offE + mm];
        #pragma unroll
        for (int j = 0; j < 4; ++j)
          ybuf[(size_t)id * HD + n0 + 64*wc + 16*j + l15] = (_Float16)acc[i][j][r];
      }
    }
}

// ---------------- combine ----------------
__global__ void k_combine(const char* __restrict__ ws, float* __restrict__ out) {
  const int idx = blockIdx.x * blockDim.x + threadIdx.x;   // over T*HD/8
  const int t = idx >> 7, c = idx & 127;
  const float* topw = (const float*)(ws + WS_TOPW);
  const _Float16* yb = (const _Float16*)(ws + WS_YBUF);
  f16x8 y0 = ((const f16x8*)(yb + (size_t)(2*t)     * HD))[c];
  f16x8 y1 = ((const f16x8*)(yb + (size_t)(2*t + 1) * HD))[c];
  const float w0 = topw[2*t], w1 = topw[2*t+1];
  f32x4 o0, o1;
  #pragma unroll
  for (int j = 0; j < 4; ++j) {
    o0[j] = w0 * (float)y0[j]     + w1 * (float)y1[j];
    o1[j] = w0 * (float)y0[4 + j] + w1 * (float)y1[4 + j];
  }
  ((f32x4*)out)[2*idx]     = o0;
  ((f32x4*)out)[2*idx + 1] = o1;
}

extern "C" void kernel_launch(void* const* d_in, const int* in_sizes, int n_in,
                              void* d_out, int out_size, void* d_ws, size_t ws_size,
                              hipStream_t stream) {
  const float* hs     = (const float*)d_in[0];
  const float* logits = (const float*)d_in[1];
  const float* Wg     = (const float*)d_in[2];
  const float* Wu     = (const float*)d_in[3];
  const float* Wd     = (const float*)d_in[4];
  char* ws = (char*)d_ws;   // requires ~295 MB of workspace

  _Float16* hs16 = (_Float16*)(ws + WS_HS16);
  _Float16* wg16 = (_Float16*)(ws + WS_WG16);
  _Float16* wu16 = (_Float16*)(ws + WS_WU16);
  _Float16* wd16 = (_Float16*)(ws + WS_WD16);

  hipMemsetAsync(ws, 0, 256, stream);
  k_router <<<dim3(T_TOK/256), dim3(256), 0, stream>>>(logits, ws);
  k_prefix <<<dim3(1),         dim3(64),  0, stream>>>(ws);
  k_scatter<<<dim3(T_TOK/256), dim3(256), 0, stream>>>(ws);
  k_hscvt  <<<dim3(T_TOK*HD/4/256), dim3(256), 0, stream>>>(hs, hs16);
  k_wtrans <<<dim3(ID/64, HD/64, NE), dim3(256), 0, stream>>>(Wg, wg16, HD, ID);
  k_wtrans <<<dim3(ID/64, HD/64, NE), dim3(256), 0, stream>>>(Wu, wu16, HD, ID);
  k_wtrans <<<dim3(HD/64, ID/64, NE), dim3(256), 0, stream>>>(Wd, wd16, ID, HD);
  k_gemm1  <<<dim3(ID/128, MAXT2), dim3(512), 0, stream>>>(hs16, wg16, wu16, ws);
  k_gemm2  <<<dim3(HD/128, MAXT2), dim3(256), 0, stream>>>(wd16, ws);
  k_combine<<<dim3(T_TOK*HD/8/256), dim3(256), 0, stream>>>(ws, (float*)d_out);
}

// Round 7
// 486.534 us; speedup vs baseline: 1.0963x; 1.0299x over previous
//
#include <hip/hip_runtime.h>

typedef float    f32x4 __attribute__((ext_vector_type(4)));
typedef _Float16 f16x8 __attribute__((ext_vector_type(8)));
typedef _Float16 f16x4 __attribute__((ext_vector_type(4)));

#define T_TOK 4096
#define HD    1024
#define ID    4096
#define NE    8
#define TOTP  (2*T_TOK)
#define MAXT1 72     // BM=128 tiles (gemm2)
#define MAXT2 40     // BM=256 tiles (gemm1)

// ---- workspace layout (bytes). Total ~295 MB ----
#define WS_CNT   0
#define WS_FILL  64
#define WS_OFF   128
#define WS_TOT   192
#define WS_TOT2  196
#define WS_TEXP  256
#define WS_TM0   (256 + 4*MAXT1)
#define WS_TEXP2 (256 + 8*MAXT1)
#define WS_TM02  (256 + 8*MAXT1 + 4*MAXT2)
#define WS_TOPE  2048
#define WS_TOPW  (WS_TOPE + 4*TOTP)
#define WS_PAIR  (WS_TOPW + 4*TOTP)
#define WS_ACT   ((size_t)1 << 20)                              // f16[TOTP*ID]   64 MB
constexpr size_t WS_YBUF = WS_ACT  + 2ull*TOTP*ID;              // (spare)        16 MB
constexpr size_t WS_HS16 = WS_YBUF + 2ull*TOTP*HD;              // f16[T*HD]       8 MB
constexpr size_t WS_WG16 = WS_HS16 + 2ull*T_TOK*HD;             // f16[E][I][H]   67 MB
constexpr size_t WS_WU16 = WS_WG16 + 2ull*NE*HD*ID;             // f16[E][I][H]   67 MB
constexpr size_t WS_WD16 = WS_WU16 + 2ull*NE*HD*ID;             // f16[E][H][I]   67 MB
// ybuf partials overlay the Wg16 region (dead after gemm1; stream order)
constexpr size_t WS_YB0  = WS_WG16;                             // f16[TOTP*HD]   16 MB
constexpr size_t WS_YB1  = WS_WG16 + 2ull*TOTP*HD;              // f16[TOTP*HD]   16 MB

// async global->LDS, 16B per lane, wave-uniform LDS base
__device__ __forceinline__ void gll16(const void* g, void* l) {
  __builtin_amdgcn_global_load_lds(
      (const __attribute__((address_space(1))) unsigned int*)g,
      (__attribute__((address_space(3))) unsigned int*)l, 16, 0, 0);
}

#define WAITV(N) do { \
    asm volatile("s_waitcnt vmcnt(" #N ")" ::: "memory"); \
    __builtin_amdgcn_sched_barrier(0); \
  } while (0)

// [row][32] f16 tile swizzle: 16B-granule XOR (2-way bank aliasing = free)
__device__ __forceinline__ int lofs(int row, int g) {
  return row * 32 + ((g ^ ((row >> 1) & 3)) << 3);
}

// ---------------- routing ----------------
__global__ void k_router(const float* __restrict__ logits, char* __restrict__ ws) {
  int t = blockIdx.x * blockDim.x + threadIdx.x;
  if (t >= T_TOK) return;
  float v0 = -1e30f, v1 = -1e30f; int i0 = 0, i1 = 0;
  #pragma unroll
  for (int e = 0; e < NE; ++e) {
    float v = logits[t * NE + e];
    if (v > v0)      { v1 = v0; i1 = i0; v0 = v; i0 = e; }
    else if (v > v1) { v1 = v;  i1 = e; }
  }
  float w0 = 1.f / (1.f + __expf(v1 - v0));
  ((int*)(ws + WS_TOPE))[2*t]   = i0;
  ((int*)(ws + WS_TOPE))[2*t+1] = i1;
  ((float*)(ws + WS_TOPW))[2*t]   = w0;
  ((float*)(ws + WS_TOPW))[2*t+1] = 1.f - w0;
  atomicAdd(&((int*)(ws + WS_CNT))[i0], 1);
  atomicAdd(&((int*)(ws + WS_CNT))[i1], 1);
}

__global__ void k_prefix(char* __restrict__ ws) {
  if (threadIdx.x != 0 || blockIdx.x != 0) return;
  const int* cnt = (const int*)(ws + WS_CNT);
  int* off   = (int*)(ws + WS_OFF);
  int* texp  = (int*)(ws + WS_TEXP);
  int* tm0   = (int*)(ws + WS_TM0);
  int* texp2 = (int*)(ws + WS_TEXP2);
  int* tm02  = (int*)(ws + WS_TM02);
  int run = 0, t1 = 0, t2 = 0;
  for (int e = 0; e < NE; ++e) {
    off[e] = run;
    int ne = cnt[e];
    for (int i = 0; i < ne; i += 128) { texp[t1] = e; tm0[t1] = i; ++t1; }
    for (int i = 0; i < ne; i += 256) { texp2[t2] = e; tm02[t2] = i; ++t2; }
    run += ne;
  }
  off[NE] = run;
  *(int*)(ws + WS_TOT)  = t1;
  *(int*)(ws + WS_TOT2) = t2;
}

__global__ void k_scatter(char* __restrict__ ws) {
  int t = blockIdx.x * blockDim.x + threadIdx.x;
  if (t >= T_TOK) return;
  const int* tope = (const int*)(ws + WS_TOPE);
  const int* off  = (const int*)(ws + WS_OFF);
  int* fill = (int*)(ws + WS_FILL);
  int* pair = (int*)(ws + WS_PAIR);
  #pragma unroll
  for (int s = 0; s < 2; ++s) {
    int id = 2*t + s;
    int e = tope[id];
    int pos = off[e] + atomicAdd(&fill[e], 1);
    pair[pos] = id;   // order nondeterministic; ybuf row = id keeps output deterministic
  }
}

// ---------------- conversions ----------------
__global__ void k_hscvt(const float* __restrict__ src, _Float16* __restrict__ dst) {
  int i = blockIdx.x * blockDim.x + threadIdx.x;
  f32x4 v = ((const f32x4*)src)[i];
  f16x4 o;
  #pragma unroll
  for (int j = 0; j < 4; ++j) o[j] = (_Float16)v[j];
  ((f16x4*)dst)[i] = o;
}

// f32 [e][K][N] -> f16 [e][N][K], 64x64 tiles via LDS
__global__ __launch_bounds__(256) void k_wtrans(const float* __restrict__ src,
                                                _Float16* __restrict__ dst,
                                                int K, int N) {
  const int e = blockIdx.z;
  const int n0 = blockIdx.x * 64, k0 = blockIdx.y * 64;
  const float* s = src + (size_t)e * K * N;
  _Float16* d = dst + (size_t)e * (size_t)K * N;
  __shared__ _Float16 t[64][68];
  const int tx = threadIdx.x & 15, ty = threadIdx.x >> 4;
  #pragma unroll
  for (int it = 0; it < 4; ++it) {
    int k = k0 + it*16 + ty;
    f32x4 v = *(const f32x4*)&s[(size_t)k * N + n0 + tx*4];
    #pragma unroll
    for (int j = 0; j < 4; ++j) t[tx*4 + j][it*16 + ty] = (_Float16)v[j];
  }
  __syncthreads();
  #pragma unroll
  for (int it = 0; it < 4; ++it) {
    int n = it*16 + ty;
    *(f16x4*)&d[(size_t)(n0 + n) * K + k0 + tx*4] = *(const f16x4*)&t[n][tx*4];
  }
}

// ---------------- GEMM1: act[p] = silu(hs@Wg) * (hs@Wu), f16 ----------------
// BM=256, BN=128 dual-B, BK=32; 8 waves (2M x 4N), wave tile 128x32 for g AND u.
// 4 LDS buffers (128 KB), depth-3 prefetch, counted vmcnt(12) steady state.
#define G1_BUF 16384   // f16/buffer: A[256][32] @0 | Bg[128][32] @8192 | Bu @12288
__global__ __launch_bounds__(512, 2) void k_gemm1(
    const _Float16* __restrict__ hs16, const _Float16* __restrict__ WgT,
    const _Float16* __restrict__ WuT, char* __restrict__ ws) {
  const int s = blockIdx.y;
  if (s >= *(const int*)(ws + WS_TOT2)) return;
  const int e    = ((const int*)(ws + WS_TEXP2))[s];
  const int m0   = ((const int*)(ws + WS_TM02))[s];
  const int offE = ((const int*)(ws + WS_OFF))[e];
  const int nE   = ((const int*)(ws + WS_CNT))[e];
  _Float16* __restrict__ act = (_Float16*)(ws + WS_ACT);
  const int n0 = blockIdx.x * 128;
  const int tid = threadIdx.x, lane = tid & 63, wid = tid >> 6;

  __shared__ __align__(16) _Float16 sm[4 * G1_BUF];   // 128 KB

  // staging lane map: 4 lanes/row (16B granules), 16 rows/gll; source granule
  // inverse-swizzled (rule 21: linear LDS dest + pre-swizzled global src)
  const int rL = lane >> 2;
  const int q  = (((lane & 3) ^ ((lane >> 3) & 3)) << 3);
  const int* __restrict__ pairp = (const int*)(ws + WS_PAIR);
  const _Float16 *aP[2], *gP, *uP;
  #pragma unroll
  for (int c = 0; c < 2; ++c) {        // A: wave stages rows 32w..32w+31
    int mm = m0 + 32*wid + 16*c + rL;
    int tok = (mm < nE) ? (pairp[offE + mm] >> 1) : 0;
    aP[c] = hs16 + (size_t)tok * HD + q;
  }
  {                                     // B: wave stages cols 16w..16w+15
    size_t col = (size_t)e * ID + (n0 + 16*wid + rL);
    gP = WgT + col * HD + q;
    uP = WuT + col * HD + q;
  }

  auto stage = [&](int buf, int kt) {   // 4 gll per wave per K-tile
    _Float16* b = sm + buf * G1_BUF;
    const int ko = kt * 32;
    gll16(aP[0] + ko, b + (32*wid) * 32);
    gll16(aP[1] + ko, b + (32*wid + 16) * 32);
    gll16(gP + ko, b + 8192  + (16*wid) * 32);
    gll16(uP + ko, b + 12288 + (16*wid) * 32);
  };

  const int wr = wid >> 2, wc = wid & 3;   // 2M x 4N
  const int l15 = lane & 15, l4 = lane >> 4;
  f32x4 accg[8][2] = {}, accu[8][2] = {};

  auto compute = [&](int buf) {          // 12 ds_read_b128, 32 MFMA
    const _Float16* b0 = sm + buf * G1_BUF;
    f16x8 afr[8], bg[2], bu[2];
    #pragma unroll
    for (int i = 0; i < 8; ++i)
      afr[i] = *(const f16x8*)&b0[lofs(128*wr + 16*i + l15, l4)];
    #pragma unroll
    for (int j = 0; j < 2; ++j) {
      bg[j] = *(const f16x8*)&b0[8192  + lofs(32*wc + 16*j + l15, l4)];
      bu[j] = *(const f16x8*)&b0[12288 + lofs(32*wc + 16*j + l15, l4)];
    }
    __builtin_amdgcn_s_setprio(1);
    #pragma unroll
    for (int i = 0; i < 8; ++i)
      #pragma unroll
      for (int j = 0; j < 2; ++j) {
        accg[i][j] = __builtin_amdgcn_mfma_f32_16x16x32_f16(afr[i], bg[j], accg[i][j], 0, 0, 0);
        accu[i][j] = __builtin_amdgcn_mfma_f32_16x16x32_f16(afr[i], bu[j], accu[i][j], 0, 0, 0);
      }
    __builtin_amdgcn_s_setprio(0);
  };

  const int KT = HD / 32;                  // 32
  stage(0, 0); stage(1, 1); stage(2, 2);
  for (int t = 0; t < KT - 3; ++t) {       // steady state: 3 tiles in flight
    stage((t + 3) & 3, t + 3);             // overwrites buf read at t-1
    WAITV(12);                             // tile t landed; t+1..t+3 in flight
    __builtin_amdgcn_s_barrier();
    compute(t & 3);
    __builtin_amdgcn_s_barrier();
  }
  WAITV(8);
  __builtin_amdgcn_s_barrier();
  compute((KT - 3) & 3);
  __builtin_amdgcn_s_barrier();
  WAITV(4);
  __builtin_amdgcn_s_barrier();
  compute((KT - 2) & 3);
  __builtin_amdgcn_s_barrier();
  WAITV(0);
  __builtin_amdgcn_s_barrier();
  compute((KT - 1) & 3);

  #pragma unroll
  for (int i = 0; i < 8; ++i)
    #pragma unroll
    for (int r = 0; r < 4; ++r) {
      const int mm = m0 + 128*wr + 16*i + 4*l4 + r;   // C/D: col=lane&15, row=(lane>>4)*4+r
      if (mm < nE) {
        const size_t prow = (size_t)(offE + mm) * ID;
        #pragma unroll
        for (int j = 0; j < 2; ++j) {
          float g = accg[i][j][r], u = accu[i][j][r];
          float sv = g / (1.f + __expf(-g)) * u;
          act[prow + n0 + 32*wc + 16*j + l15] = (_Float16)sv;
        }
      }
    }
}

// ---------------- GEMM2: ybuf_h[id] = act[p][kh] @ WdT[e][kh] (K-split) ------
// BM=128, BN=256, BK=32, K-split 2; 4 waves (2x2), wave tile 64x128;
// 3 bufs (72 KB) depth-2 counted vmcnt(12). 576 blocks -> GPU full.
#define G2_BUF 12288   // f16/buffer: A[128][32] @0 | B[256][32] @4096
__global__ __launch_bounds__(256, 2) void k_gemm2(const _Float16* __restrict__ WdT,
                                                  char* __restrict__ ws) {
  const int s = blockIdx.y;
  if (s >= *(const int*)(ws + WS_TOT)) return;
  const int e    = ((const int*)(ws + WS_TEXP))[s];
  const int m0   = ((const int*)(ws + WS_TM0))[s];
  const int offE = ((const int*)(ws + WS_OFF))[e];
  const int nE   = ((const int*)(ws + WS_CNT))[e];
  const int h    = blockIdx.z;             // K half
  const int kbase = h * (ID / 2);
  const int* __restrict__ pair = (const int*)(ws + WS_PAIR);
  const _Float16* __restrict__ act = (const _Float16*)(ws + WS_ACT);
  _Float16* __restrict__ yb = (_Float16*)(ws + (h ? WS_YB1 : WS_YB0));
  const int n0 = blockIdx.x * 256;
  const int tid = threadIdx.x, lane = tid & 63, wid = tid >> 6;

  __shared__ __align__(16) _Float16 sm[3 * G2_BUF];   // 72 KB

  const int rL = lane >> 2;
  const int q  = (((lane & 3) ^ ((lane >> 3) & 3)) << 3);
  const _Float16 *aS[2], *bS[4];
  #pragma unroll
  for (int c = 0; c < 2; ++c) {          // A: wave stages rows 32w..32w+31
    int mm = m0 + 32*wid + 16*c + rL;
    int p = (mm < nE) ? (offE + mm) : offE;
    aS[c] = act + (size_t)p * ID + kbase + q;
  }
  #pragma unroll
  for (int c = 0; c < 4; ++c)            // B: wave stages cols 64w..64w+63
    bS[c] = WdT + ((size_t)e * HD + (n0 + 64*wid + 16*c + rL)) * ID + kbase + q;

  auto stage = [&](int buf, int kt) {    // 6 gll per wave per K-tile
    _Float16* b = sm + buf * G2_BUF;
    const int ko = kt * 32;
    #pragma unroll
    for (int c = 0; c < 2; ++c) gll16(aS[c] + ko, b + (32*wid + 16*c) * 32);
    #pragma unroll
    for (int c = 0; c < 4; ++c) gll16(bS[c] + ko, b + 4096 + (64*wid + 16*c) * 32);
  };

  const int wr = wid >> 1, wc = wid & 1;   // 2M x 2N waves, tile 64x128
  const int l15 = lane & 15, l4 = lane >> 4;
  f32x4 acc[4][8] = {};

  auto compute = [&](int buf) {            // 12 ds_read_b128, 32 MFMA
    const _Float16* b0 = sm + buf * G2_BUF;
    f16x8 afr[4], bfr[8];
    #pragma unroll
    for (int i = 0; i < 4; ++i)
      afr[i] = *(const f16x8*)&b0[lofs(64*wr + 16*i + l15, l4)];
    #pragma unroll
    for (int j = 0; j < 8; ++j)
      bfr[j] = *(const f16x8*)&b0[4096 + lofs(128*wc + 16*j + l15, l4)];
    __builtin_amdgcn_s_setprio(1);
    #pragma unroll
    for (int i = 0; i < 4; ++i)
      #pragma unroll
      for (int j = 0; j < 8; ++j)
        acc[i][j] = __builtin_amdgcn_mfma_f32_16x16x32_f16(afr[i], bfr[j], acc[i][j], 0, 0, 0);
    __builtin_amdgcn_s_setprio(0);
  };

  const int KT = (ID / 2) / 32;            // 64
  stage(0, 0); stage(1, 1);
  for (int t = 0; t < KT - 2; ++t) {
    stage((t + 2) % 3, t + 2);
    WAITV(12);                             // tile t landed; t+1,t+2 in flight
    __builtin_amdgcn_s_barrier();
    compute(t % 3);
    __builtin_amdgcn_s_barrier();
  }
  WAITV(6);
  __builtin_amdgcn_s_barrier();
  compute((KT - 2) % 3);
  __builtin_amdgcn_s_barrier();
  WAITV(0);
  __builtin_amdgcn_s_barrier();
  compute((KT - 1) % 3);

  #pragma unroll
  for (int i = 0; i < 4; ++i)
    #pragma unroll
    for (int r = 0; r < 4; ++r) {
      const int mm = m0 + 64*wr + 16*i + 4*l4 + r;
      if (mm < nE) {
        const int id = pair[offE + mm];
        #pragma unroll
        for (int j = 0; j < 8; ++j)
          yb[(size_t)id * HD + n0 + 128*wc + 16*j + l15] = (_Float16)acc[i][j][r];
      }
    }
}

// ---------------- combine: out[t] = w0*(y0a+y0b) + w1*(y1a+y1b) --------------
__global__ void k_combine(const char* __restrict__ ws, float* __restrict__ out) {
  const int idx = blockIdx.x * blockDim.x + threadIdx.x;   // over T*HD/8
  const int t = idx >> 7, c = idx & 127;
  const float* topw = (const float*)(ws + WS_TOPW);
  const _Float16* y0p = (const _Float16*)(ws + WS_YB0);
  const _Float16* y1p = (const _Float16*)(ws + WS_YB1);
  f16x8 a0 = ((const f16x8*)(y0p + (size_t)(2*t)     * HD))[c];
  f16x8 b0 = ((const f16x8*)(y1p + (size_t)(2*t)     * HD))[c];
  f16x8 a1 = ((const f16x8*)(y0p + (size_t)(2*t + 1) * HD))[c];
  f16x8 b1 = ((const f16x8*)(y1p + (size_t)(2*t + 1) * HD))[c];
  const float w0 = topw[2*t], w1 = topw[2*t+1];
  f32x4 o0, o1;
  #pragma unroll
  for (int j = 0; j < 4; ++j) {
    o0[j] = w0 * ((float)a0[j]     + (float)b0[j])     + w1 * ((float)a1[j]     + (float)b1[j]);
    o1[j] = w0 * ((float)a0[4 + j] + (float)b0[4 + j]) + w1 * ((float)a1[4 + j] + (float)b1[4 + j]);
  }
  ((f32x4*)out)[2*idx]     = o0;
  ((f32x4*)out)[2*idx + 1] = o1;
}

extern "C" void kernel_launch(void* const* d_in, const int* in_sizes, int n_in,
                              void* d_out, int out_size, void* d_ws, size_t ws_size,
                              hipStream_t stream) {
  const float* hs     = (const float*)d_in[0];
  const float* logits = (const float*)d_in[1];
  const float* Wg     = (const float*)d_in[2];
  const float* Wu     = (const float*)d_in[3];
  const float* Wd     = (const float*)d_in[4];
  char* ws = (char*)d_ws;   // requires ~295 MB of workspace

  _Float16* hs16 = (_Float16*)(ws + WS_HS16);
  _Float16* wg16 = (_Float16*)(ws + WS_WG16);
  _Float16* wu16 = (_Float16*)(ws + WS_WU16);
  _Float16* wd16 = (_Float16*)(ws + WS_WD16);

  hipMemsetAsync(ws, 0, 256, stream);
  k_router <<<dim3(T_TOK/256), dim3(256), 0, stream>>>(logits, ws);
  k_prefix <<<dim3(1),         dim3(64),  0, stream>>>(ws);
  k_scatter<<<dim3(T_TOK/256), dim3(256), 0, stream>>>(ws);
  k_hscvt  <<<dim3(T_TOK*HD/4/256), dim3(256), 0, stream>>>(hs, hs16);
  k_wtrans <<<dim3(ID/64, HD/64, NE), dim3(256), 0, stream>>>(Wg, wg16, HD, ID);
  k_wtrans <<<dim3(ID/64, HD/64, NE), dim3(256), 0, stream>>>(Wu, wu16, HD, ID);
  k_wtrans <<<dim3(HD/64, ID/64, NE), dim3(256), 0, stream>>>(Wd, wd16, ID, HD);
  k_gemm1  <<<dim3(ID/128, MAXT2),    dim3(512), 0, stream>>>(hs16, wg16, wu16, ws);
  k_gemm2  <<<dim3(HD/256, MAXT1, 2), dim3(256), 0, stream>>>(wd16, ws);
  k_combine<<<dim3(T_TOK*HD/8/256), dim3(256), 0, stream>>>(ws, (float*)d_out);
}

// Round 8
// 482.232 us; speedup vs baseline: 1.1061x; 1.0089x over previous
//
#include <hip/hip_runtime.h>

typedef float    f32x4 __attribute__((ext_vector_type(4)));
typedef _Float16 f16x8 __attribute__((ext_vector_type(8)));
typedef _Float16 f16x4 __attribute__((ext_vector_type(4)));

#define T_TOK 4096
#define HD    1024
#define ID    4096
#define NE    8
#define TOTP  (2*T_TOK)
#define MAXT1 72     // BM=128 tiles (gemm2)
#define MAXT2 40     // BM=256 tiles (gemm1)

// ---- workspace layout (bytes). Total ~295 MB ----
#define WS_CNT   0
#define WS_FILL  64
#define WS_OFF   128
#define WS_TOT   192
#define WS_TOT2  196
#define WS_TEXP  256
#define WS_TM0   (256 + 4*MAXT1)
#define WS_TEXP2 (256 + 8*MAXT1)
#define WS_TM02  (256 + 8*MAXT1 + 4*MAXT2)
#define WS_TOPE  2048
#define WS_TOPW  (WS_TOPE + 4*TOTP)
#define WS_PAIR  (WS_TOPW + 4*TOTP)
#define WS_ACT   ((size_t)1 << 20)                              // f16[TOTP*ID]   64 MB
constexpr size_t WS_YBUF = WS_ACT  + 2ull*TOTP*ID;              // (spare)        16 MB
constexpr size_t WS_HS16 = WS_YBUF + 2ull*TOTP*HD;              // f16[T*HD]       8 MB
constexpr size_t WS_WG16 = WS_HS16 + 2ull*T_TOK*HD;             // f16[E][I][H]   67 MB
constexpr size_t WS_WU16 = WS_WG16 + 2ull*NE*HD*ID;             // f16[E][I][H]   67 MB
constexpr size_t WS_WD16 = WS_WU16 + 2ull*NE*HD*ID;             // f16[E][H][I]   67 MB
// ybuf partials overlay the Wg16 region (dead after gemm1; stream order)
constexpr size_t WS_YB0  = WS_WG16;                             // f16[TOTP*HD]   16 MB
constexpr size_t WS_YB1  = WS_WG16 + 2ull*TOTP*HD;              // f16[TOTP*HD]   16 MB

// async global->LDS, 16B per lane, wave-uniform LDS base
__device__ __forceinline__ void gll16(const void* g, void* l) {
  __builtin_amdgcn_global_load_lds(
      (const __attribute__((address_space(1))) unsigned int*)g,
      (__attribute__((address_space(3))) unsigned int*)l, 16, 0, 0);
}

#define WAITV(N) do { \
    asm volatile("s_waitcnt vmcnt(" #N ")" ::: "memory"); \
    __builtin_amdgcn_sched_barrier(0); \
  } while (0)

#define LGKM0 do { \
    asm volatile("s_waitcnt lgkmcnt(0)" ::: "memory"); \
    __builtin_amdgcn_sched_barrier(0); \
  } while (0)

// [row][32] f16 tile swizzle: 16B-granule XOR (2-way bank aliasing = free)
__device__ __forceinline__ int lofs(int row, int g) {
  return row * 32 + ((g ^ ((row >> 1) & 3)) << 3);
}

// ---------------- routing ----------------
__global__ void k_router(const float* __restrict__ logits, char* __restrict__ ws) {
  int t = blockIdx.x * blockDim.x + threadIdx.x;
  if (t >= T_TOK) return;
  float v0 = -1e30f, v1 = -1e30f; int i0 = 0, i1 = 0;
  #pragma unroll
  for (int e = 0; e < NE; ++e) {
    float v = logits[t * NE + e];
    if (v > v0)      { v1 = v0; i1 = i0; v0 = v; i0 = e; }
    else if (v > v1) { v1 = v;  i1 = e; }
  }
  float w0 = 1.f / (1.f + __expf(v1 - v0));
  ((int*)(ws + WS_TOPE))[2*t]   = i0;
  ((int*)(ws + WS_TOPE))[2*t+1] = i1;
  ((float*)(ws + WS_TOPW))[2*t]   = w0;
  ((float*)(ws + WS_TOPW))[2*t+1] = 1.f - w0;
  atomicAdd(&((int*)(ws + WS_CNT))[i0], 1);
  atomicAdd(&((int*)(ws + WS_CNT))[i1], 1);
}

__global__ void k_prefix(char* __restrict__ ws) {
  if (threadIdx.x != 0 || blockIdx.x != 0) return;
  const int* cnt = (const int*)(ws + WS_CNT);
  int* off   = (int*)(ws + WS_OFF);
  int* texp  = (int*)(ws + WS_TEXP);
  int* tm0   = (int*)(ws + WS_TM0);
  int* texp2 = (int*)(ws + WS_TEXP2);
  int* tm02  = (int*)(ws + WS_TM02);
  int run = 0, t1 = 0, t2 = 0;
  for (int e = 0; e < NE; ++e) {
    off[e] = run;
    int ne = cnt[e];
    for (int i = 0; i < ne; i += 128) { texp[t1] = e; tm0[t1] = i; ++t1; }
    for (int i = 0; i < ne; i += 256) { texp2[t2] = e; tm02[t2] = i; ++t2; }
    run += ne;
  }
  off[NE] = run;
  *(int*)(ws + WS_TOT)  = t1;
  *(int*)(ws + WS_TOT2) = t2;
}

__global__ void k_scatter(char* __restrict__ ws) {
  int t = blockIdx.x * blockDim.x + threadIdx.x;
  if (t >= T_TOK) return;
  const int* tope = (const int*)(ws + WS_TOPE);
  const int* off  = (const int*)(ws + WS_OFF);
  int* fill = (int*)(ws + WS_FILL);
  int* pair = (int*)(ws + WS_PAIR);
  #pragma unroll
  for (int s = 0; s < 2; ++s) {
    int id = 2*t + s;
    int e = tope[id];
    int pos = off[e] + atomicAdd(&fill[e], 1);
    pair[pos] = id;   // order nondeterministic; ybuf row = id keeps output deterministic
  }
}

// ---------------- conversions ----------------
__global__ void k_hscvt(const float* __restrict__ src, _Float16* __restrict__ dst) {
  int i = blockIdx.x * blockDim.x + threadIdx.x;
  f32x4 v = ((const f32x4*)src)[i];
  f16x4 o;
  #pragma unroll
  for (int j = 0; j < 4; ++j) o[j] = (_Float16)v[j];
  ((f16x4*)dst)[i] = o;
}

// f32 [e][K][N] -> f16 [e][N][K], 64x64 tiles via LDS
__global__ __launch_bounds__(256) void k_wtrans(const float* __restrict__ src,
                                                _Float16* __restrict__ dst,
                                                int K, int N) {
  const int e = blockIdx.z;
  const int n0 = blockIdx.x * 64, k0 = blockIdx.y * 64;
  const float* s = src + (size_t)e * K * N;
  _Float16* d = dst + (size_t)e * (size_t)K * N;
  __shared__ _Float16 t[64][68];
  const int tx = threadIdx.x & 15, ty = threadIdx.x >> 4;
  #pragma unroll
  for (int it = 0; it < 4; ++it) {
    int k = k0 + it*16 + ty;
    f32x4 v = *(const f32x4*)&s[(size_t)k * N + n0 + tx*4];
    #pragma unroll
    for (int j = 0; j < 4; ++j) t[tx*4 + j][it*16 + ty] = (_Float16)v[j];
  }
  __syncthreads();
  #pragma unroll
  for (int it = 0; it < 4; ++it) {
    int n = it*16 + ty;
    *(f16x4*)&d[(size_t)(n0 + n) * K + k0 + tx*4] = *(const f16x4*)&t[n][tx*4];
  }
}

// ---------------- GEMM1: act[p] = silu(hs@Wg) * (hs@Wu), f16 ----------------
// 8-phase-template port: BM=256, dual-B 128+128, BK=32; 8 waves (2M x 4N);
// 2 phases/K-tile x 16 MFMA; 4 LDS buffers (128 KB); prefetch dist 3,
// steady vmcnt(8) once per K-tile (epilogue 8->4->0).
#define G1_BUF 16384   // f16/buffer: A[256][32] @0 | Bg[128][32] @8192 | Bu @12288
__global__ __launch_bounds__(512, 2) void k_gemm1(
    const _Float16* __restrict__ hs16, const _Float16* __restrict__ WgT,
    const _Float16* __restrict__ WuT, char* __restrict__ ws) {
  const int s = blockIdx.y;
  if (s >= *(const int*)(ws + WS_TOT2)) return;
  const int e    = ((const int*)(ws + WS_TEXP2))[s];
  const int m0   = ((const int*)(ws + WS_TM02))[s];
  const int offE = ((const int*)(ws + WS_OFF))[e];
  const int nE   = ((const int*)(ws + WS_CNT))[e];
  _Float16* __restrict__ act = (_Float16*)(ws + WS_ACT);
  const int n0 = blockIdx.x * 128;
  const int tid = threadIdx.x, lane = tid & 63, wid = tid >> 6;

  __shared__ __align__(16) _Float16 sm[4 * G1_BUF];   // 128 KB

  // staging lane map: 4 lanes/row (16B granules), 16 rows/gll; source granule
  // inverse-swizzled (rule 21: linear LDS dest + pre-swizzled global src)
  const int rL = lane >> 2;
  const int q  = (((lane & 3) ^ ((lane >> 3) & 3)) << 3);
  const int* __restrict__ pairp = (const int*)(ws + WS_PAIR);
  const _Float16 *aP[2], *gP, *uP;
  #pragma unroll
  for (int c = 0; c < 2; ++c) {        // A: wave stages rows 32w..32w+31
    int mm = m0 + 32*wid + 16*c + rL;
    int tok = (mm < nE) ? (pairp[offE + mm] >> 1) : 0;
    aP[c] = hs16 + (size_t)tok * HD + q;
  }
  {                                     // B: wave stages cols 16w..16w+15
    size_t col = (size_t)e * ID + (n0 + 16*wid + rL);
    gP = WgT + col * HD + q;
    uP = WuT + col * HD + q;
  }

  auto stA = [&](int buf, int kt) {     // 2 gll: A rows
    _Float16* b = sm + buf * G1_BUF;
    const int ko = kt * 32;
    gll16(aP[0] + ko, b + (32*wid) * 32);
    gll16(aP[1] + ko, b + (32*wid + 16) * 32);
  };
  auto stB = [&](int buf, int kt) {     // 2 gll: Bg + Bu cols
    _Float16* b = sm + buf * G1_BUF;
    const int ko = kt * 32;
    gll16(gP + ko, b + 8192  + (16*wid) * 32);
    gll16(uP + ko, b + 12288 + (16*wid) * 32);
  };

  const int wr = wid >> 2, wc = wid & 3;   // 2M x 4N
  const int l15 = lane & 15, l4 = lane >> 4;
  f32x4 accg[8][2] = {}, accu[8][2] = {};
  f16x8 afr[4], bg[2], bu[2];

  auto rd0 = [&](int buf) {             // A mh0 (4) + Bg (2) + Bu (2)
    const _Float16* b0 = sm + buf * G1_BUF;
    #pragma unroll
    for (int i = 0; i < 4; ++i)
      afr[i] = *(const f16x8*)&b0[lofs(128*wr + 16*i + l15, l4)];
    #pragma unroll
    for (int j = 0; j < 2; ++j) {
      bg[j] = *(const f16x8*)&b0[8192  + lofs(32*wc + 16*j + l15, l4)];
      bu[j] = *(const f16x8*)&b0[12288 + lofs(32*wc + 16*j + l15, l4)];
    }
  };
  auto rd1 = [&](int buf) {             // A mh1 (4); B frags reused
    const _Float16* b0 = sm + buf * G1_BUF;
    #pragma unroll
    for (int i = 0; i < 4; ++i)
      afr[i] = *(const f16x8*)&b0[lofs(128*wr + 64 + 16*i + l15, l4)];
  };
  auto fma0 = [&]() {                   // 16 MFMA, mh0
    __builtin_amdgcn_s_barrier();
    LGKM0;
    __builtin_amdgcn_s_setprio(1);
    #pragma unroll
    for (int i = 0; i < 4; ++i)
      #pragma unroll
      for (int j = 0; j < 2; ++j) {
        accg[i][j] = __builtin_amdgcn_mfma_f32_16x16x32_f16(afr[i], bg[j], accg[i][j], 0, 0, 0);
        accu[i][j] = __builtin_amdgcn_mfma_f32_16x16x32_f16(afr[i], bu[j], accu[i][j], 0, 0, 0);
      }
    __builtin_amdgcn_s_setprio(0);
    __builtin_amdgcn_s_barrier();
  };
  auto fma1 = [&]() {                   // 16 MFMA, mh1
    __builtin_amdgcn_s_barrier();
    LGKM0;
    __builtin_amdgcn_s_setprio(1);
    #pragma unroll
    for (int i = 0; i < 4; ++i)
      #pragma unroll
      for (int j = 0; j < 2; ++j) {
        accg[4+i][j] = __builtin_amdgcn_mfma_f32_16x16x32_f16(afr[i], bg[j], accg[4+i][j], 0, 0, 0);
        accu[4+i][j] = __builtin_amdgcn_mfma_f32_16x16x32_f16(afr[i], bu[j], accu[4+i][j], 0, 0, 0);
      }
    __builtin_amdgcn_s_setprio(0);
    __builtin_amdgcn_s_barrier();
  };

  const int KT = HD / 32;                  // 32
  // prologue: tiles 0..2 in flight, wait tile 0 (8 = tiles 1,2 outstanding)
  stA(0, 0); stB(0, 0); stA(1, 1); stB(1, 1); stA(2, 2); stB(2, 2);
  WAITV(8);
  __builtin_amdgcn_s_barrier();
  for (int t = 0; t < KT - 3; ++t) {
    const int buf = t & 3, nb = (t + 3) & 3;
    rd0(buf); stA(nb, t + 3); fma0();
    rd1(buf); stB(nb, t + 3); WAITV(8); fma1();
  }
  rd0((KT-3) & 3); fma0(); rd1((KT-3) & 3); WAITV(4); fma1();
  rd0((KT-2) & 3); fma0(); rd1((KT-2) & 3); WAITV(0); fma1();
  rd0((KT-1) & 3); fma0(); rd1((KT-1) & 3); fma1();

  #pragma unroll
  for (int i = 0; i < 8; ++i)
    #pragma unroll
    for (int r = 0; r < 4; ++r) {
      const int mm = m0 + 128*wr + 16*i + 4*l4 + r;   // C/D: col=lane&15, row=(lane>>4)*4+r
      if (mm < nE) {
        const size_t prow = (size_t)(offE + mm) * ID;
        #pragma unroll
        for (int j = 0; j < 2; ++j) {
          float g = accg[i][j][r], u = accu[i][j][r];
          float sv = g / (1.f + __expf(-g)) * u;
          act[prow + n0 + 32*wc + 16*j + l15] = (_Float16)sv;
        }
      }
    }
}

// ---------------- GEMM2: ybuf_h[id] = act[p][kh] @ WdT[e][kh] (K-split) ------
// BM=128, BN=256, BK=32, K-split 2; 4 waves (2x2), wave tile 64x128;
// 3 bufs (72 KB) depth-2 counted vmcnt(12). 576 blocks -> GPU full.
#define G2_BUF 12288   // f16/buffer: A[128][32] @0 | B[256][32] @4096
__global__ __launch_bounds__(256, 2) void k_gemm2(const _Float16* __restrict__ WdT,
                                                  char* __restrict__ ws) {
  const int s = blockIdx.y;
  if (s >= *(const int*)(ws + WS_TOT)) return;
  const int e    = ((const int*)(ws + WS_TEXP))[s];
  const int m0   = ((const int*)(ws + WS_TM0))[s];
  const int offE = ((const int*)(ws + WS_OFF))[e];
  const int nE   = ((const int*)(ws + WS_CNT))[e];
  const int h    = blockIdx.z;             // K half
  const int kbase = h * (ID / 2);
  const int* __restrict__ pair = (const int*)(ws + WS_PAIR);
  const _Float16* __restrict__ act = (const _Float16*)(ws + WS_ACT);
  _Float16* __restrict__ yb = (_Float16*)(ws + (h ? WS_YB1 : WS_YB0));
  const int n0 = blockIdx.x * 256;
  const int tid = threadIdx.x, lane = tid & 63, wid = tid >> 6;

  __shared__ __align__(16) _Float16 sm[3 * G2_BUF];   // 72 KB

  const int rL = lane >> 2;
  const int q  = (((lane & 3) ^ ((lane >> 3) & 3)) << 3);
  const _Float16 *aS[2], *bS[4];
  #pragma unroll
  for (int c = 0; c < 2; ++c) {          // A: wave stages rows 32w..32w+31
    int mm = m0 + 32*wid + 16*c + rL;
    int p = (mm < nE) ? (offE + mm) : offE;
    aS[c] = act + (size_t)p * ID + kbase + q;
  }
  #pragma unroll
  for (int c = 0; c < 4; ++c)            // B: wave stages cols 64w..64w+63
    bS[c] = WdT + ((size_t)e * HD + (n0 + 64*wid + 16*c + rL)) * ID + kbase + q;

  auto stage = [&](int buf, int kt) {    // 6 gll per wave per K-tile
    _Float16* b = sm + buf * G2_BUF;
    const int ko = kt * 32;
    #pragma unroll
    for (int c = 0; c < 2; ++c) gll16(aS[c] + ko, b + (32*wid + 16*c) * 32);
    #pragma unroll
    for (int c = 0; c < 4; ++c) gll16(bS[c] + ko, b + 4096 + (64*wid + 16*c) * 32);
  };

  const int wr = wid >> 1, wc = wid & 1;   // 2M x 2N waves, tile 64x128
  const int l15 = lane & 15, l4 = lane >> 4;
  f32x4 acc[4][8] = {};

  auto compute = [&](int buf) {            // 12 ds_read_b128, 32 MFMA
    const _Float16* b0 = sm + buf * G2_BUF;
    f16x8 afr[4], bfr[8];
    #pragma unroll
    for (int i = 0; i < 4; ++i)
      afr[i] = *(const f16x8*)&b0[lofs(64*wr + 16*i + l15, l4)];
    #pragma unroll
    for (int j = 0; j < 8; ++j)
      bfr[j] = *(const f16x8*)&b0[4096 + lofs(128*wc + 16*j + l15, l4)];
    __builtin_amdgcn_s_setprio(1);
    #pragma unroll
    for (int i = 0; i < 4; ++i)
      #pragma unroll
      for (int j = 0; j < 8; ++j)
        acc[i][j] = __builtin_amdgcn_mfma_f32_16x16x32_f16(afr[i], bfr[j], acc[i][j], 0, 0, 0);
    __builtin_amdgcn_s_setprio(0);
  };

  const int KT = (ID / 2) / 32;            // 64
  stage(0, 0); stage(1, 1);
  for (int t = 0; t < KT - 2; ++t) {
    stage((t + 2) % 3, t + 2);
    WAITV(12);                             // tile t landed; t+1,t+2 in flight
    __builtin_amdgcn_s_barrier();
    compute(t % 3);
    __builtin_amdgcn_s_barrier();
  }
  WAITV(6);
  __builtin_amdgcn_s_barrier();
  compute((KT - 2) % 3);
  __builtin_amdgcn_s_barrier();
  WAITV(0);
  __builtin_amdgcn_s_barrier();
  compute((KT - 1) % 3);

  #pragma unroll
  for (int i = 0; i < 4; ++i)
    #pragma unroll
    for (int r = 0; r < 4; ++r) {
      const int mm = m0 + 64*wr + 16*i + 4*l4 + r;
      if (mm < nE) {
        const int id = pair[offE + mm];
        #pragma unroll
        for (int j = 0; j < 8; ++j)
          yb[(size_t)id * HD + n0 + 128*wc + 16*j + l15] = (_Float16)acc[i][j][r];
      }
    }
}

// ---------------- combine: out[t] = w0*(y0a+y0b) + w1*(y1a+y1b) --------------
__global__ void k_combine(const char* __restrict__ ws, float* __restrict__ out) {
  const int idx = blockIdx.x * blockDim.x + threadIdx.x;   // over T*HD/8
  const int t = idx >> 7, c = idx & 127;
  const float* topw = (const float*)(ws + WS_TOPW);
  const _Float16* y0p = (const _Float16*)(ws + WS_YB0);
  const _Float16* y1p = (const _Float16*)(ws + WS_YB1);
  f16x8 a0 = ((const f16x8*)(y0p + (size_t)(2*t)     * HD))[c];
  f16x8 b0 = ((const f16x8*)(y1p + (size_t)(2*t)     * HD))[c];
  f16x8 a1 = ((const f16x8*)(y0p + (size_t)(2*t + 1) * HD))[c];
  f16x8 b1 = ((const f16x8*)(y1p + (size_t)(2*t + 1) * HD))[c];
  const float w0 = topw[2*t], w1 = topw[2*t+1];
  f32x4 o0, o1;
  #pragma unroll
  for (int j = 0; j < 4; ++j) {
    o0[j] = w0 * ((float)a0[j]     + (float)b0[j])     + w1 * ((float)a1[j]     + (float)b1[j]);
    o1[j] = w0 * ((float)a0[4 + j] + (float)b0[4 + j]) + w1 * ((float)a1[4 + j] + (float)b1[4 + j]);
  }
  ((f32x4*)out)[2*idx]     = o0;
  ((f32x4*)out)[2*idx + 1] = o1;
}

extern "C" void kernel_launch(void* const* d_in, const int* in_sizes, int n_in,
                              void* d_out, int out_size, void* d_ws, size_t ws_size,
                              hipStream_t stream) {
  const float* hs     = (const float*)d_in[0];
  const float* logits = (const float*)d_in[1];
  const float* Wg     = (const float*)d_in[2];
  const float* Wu     = (const float*)d_in[3];
  const float* Wd     = (const float*)d_in[4];
  char* ws = (char*)d_ws;   // requires ~295 MB of workspace

  _Float16* hs16 = (_Float16*)(ws + WS_HS16);
  _Float16* wg16 = (_Float16*)(ws + WS_WG16);
  _Float16* wu16 = (_Float16*)(ws + WS_WU16);
  _Float16* wd16 = (_Float16*)(ws + WS_WD16);

  hipMemsetAsync(ws, 0, 256, stream);
  k_router <<<dim3(T_TOK/256), dim3(256), 0, stream>>>(logits, ws);
  k_prefix <<<dim3(1),         dim3(64),  0, stream>>>(ws);
  k_scatter<<<dim3(T_TOK/256), dim3(256), 0, stream>>>(ws);
  k_hscvt  <<<dim3(T_TOK*HD/4/256), dim3(256), 0, stream>>>(hs, hs16);
  k_wtrans <<<dim3(ID/64, HD/64, NE), dim3(256), 0, stream>>>(Wg, wg16, HD, ID);
  k_wtrans <<<dim3(ID/64, HD/64, NE), dim3(256), 0, stream>>>(Wu, wu16, HD, ID);
  k_wtrans <<<dim3(HD/64, ID/64, NE), dim3(256), 0, stream>>>(Wd, wd16, ID, HD);
  k_gemm1  <<<dim3(ID/128, MAXT2),    dim3(512), 0, stream>>>(hs16, wg16, wu16, ws);
  k_gemm2  <<<dim3(HD/256, MAXT1, 2), dim3(256), 0, stream>>>(wd16, ws);
  k_combine<<<dim3(T_TOK*HD/8/256), dim3(256), 0, stream>>>(ws, (float*)d_out);
}

// Round 9
// 479.882 us; speedup vs baseline: 1.1115x; 1.0049x over previous
//
#include <hip/hip_runtime.h>

typedef float    f32x4 __attribute__((ext_vector_type(4)));
typedef _Float16 f16x8 __attribute__((ext_vector_type(8)));
typedef _Float16 f16x4 __attribute__((ext_vector_type(4)));

#define T_TOK 4096
#define HD    1024
#define ID    4096
#define NE    8
#define TOTP  (2*T_TOK)
#define MAXT1 72     // BM=128 tiles (legacy, unused by gemms)
#define MAXT2 40     // BM=256 tiles (gemm1 + gemm2)

// ---- workspace layout (bytes). Total ~295 MB ----
#define WS_CNT   0
#define WS_FILL  64
#define WS_OFF   128
#define WS_TOT   192
#define WS_TOT2  196
#define WS_TEXP  256
#define WS_TM0   (256 + 4*MAXT1)
#define WS_TEXP2 (256 + 8*MAXT1)
#define WS_TM02  (256 + 8*MAXT1 + 4*MAXT2)
#define WS_TOPE  2048
#define WS_TOPW  (WS_TOPE + 4*TOTP)
#define WS_PAIR  (WS_TOPW + 4*TOTP)
#define WS_ACT   ((size_t)1 << 20)                              // f16[TOTP*ID]   64 MB
constexpr size_t WS_YBUF = WS_ACT  + 2ull*TOTP*ID;              // (spare)        16 MB
constexpr size_t WS_HS16 = WS_YBUF + 2ull*TOTP*HD;              // f16[T*HD]       8 MB
constexpr size_t WS_WG16 = WS_HS16 + 2ull*T_TOK*HD;             // f16[E][I][H]   67 MB
constexpr size_t WS_WU16 = WS_WG16 + 2ull*NE*HD*ID;             // f16[E][I][H]   67 MB
constexpr size_t WS_WD16 = WS_WU16 + 2ull*NE*HD*ID;             // f16[E][H][I]   67 MB
// 4 ybuf K-split partials overlay the Wg16 region (dead after gemm1): 4x16.8 MB
constexpr size_t WS_YB   = WS_WG16;                             // f16[4][TOTP*HD]

// async global->LDS, 16B per lane, wave-uniform LDS base
__device__ __forceinline__ void gll16(const void* g, void* l) {
  __builtin_amdgcn_global_load_lds(
      (const __attribute__((address_space(1))) unsigned int*)g,
      (__attribute__((address_space(3))) unsigned int*)l, 16, 0, 0);
}

#define WAITV(N) do { \
    asm volatile("s_waitcnt vmcnt(" #N ")" ::: "memory"); \
    __builtin_amdgcn_sched_barrier(0); \
  } while (0)

// [row][64] f16 tile swizzle (BK=64): 8 granules XOR row&7 (bases 8-aligned)
__device__ __forceinline__ int lofs64(int row, int g8) {
  return row * 64 + ((g8 ^ (row & 7)) << 3);
}

// ---------------- routing ----------------
__global__ void k_router(const float* __restrict__ logits, char* __restrict__ ws) {
  int t = blockIdx.x * blockDim.x + threadIdx.x;
  if (t >= T_TOK) return;
  float v0 = -1e30f, v1 = -1e30f; int i0 = 0, i1 = 0;
  #pragma unroll
  for (int e = 0; e < NE; ++e) {
    float v = logits[t * NE + e];
    if (v > v0)      { v1 = v0; i1 = i0; v0 = v; i0 = e; }
    else if (v > v1) { v1 = v;  i1 = e; }
  }
  float w0 = 1.f / (1.f + __expf(v1 - v0));
  ((int*)(ws + WS_TOPE))[2*t]   = i0;
  ((int*)(ws + WS_TOPE))[2*t+1] = i1;
  ((float*)(ws + WS_TOPW))[2*t]   = w0;
  ((float*)(ws + WS_TOPW))[2*t+1] = 1.f - w0;
  atomicAdd(&((int*)(ws + WS_CNT))[i0], 1);
  atomicAdd(&((int*)(ws + WS_CNT))[i1], 1);
}

__global__ void k_prefix(char* __restrict__ ws) {
  if (threadIdx.x != 0 || blockIdx.x != 0) return;
  const int* cnt = (const int*)(ws + WS_CNT);
  int* off   = (int*)(ws + WS_OFF);
  int* texp  = (int*)(ws + WS_TEXP);
  int* tm0   = (int*)(ws + WS_TM0);
  int* texp2 = (int*)(ws + WS_TEXP2);
  int* tm02  = (int*)(ws + WS_TM02);
  int run = 0, t1 = 0, t2 = 0;
  for (int e = 0; e < NE; ++e) {
    off[e] = run;
    int ne = cnt[e];
    for (int i = 0; i < ne; i += 128) { texp[t1] = e; tm0[t1] = i; ++t1; }
    for (int i = 0; i < ne; i += 256) { texp2[t2] = e; tm02[t2] = i; ++t2; }
    run += ne;
  }
  off[NE] = run;
  *(int*)(ws + WS_TOT)  = t1;
  *(int*)(ws + WS_TOT2) = t2;
}

__global__ void k_scatter(char* __restrict__ ws) {
  int t = blockIdx.x * blockDim.x + threadIdx.x;
  if (t >= T_TOK) return;
  const int* tope = (const int*)(ws + WS_TOPE);
  const int* off  = (const int*)(ws + WS_OFF);
  int* fill = (int*)(ws + WS_FILL);
  int* pair = (int*)(ws + WS_PAIR);
  #pragma unroll
  for (int s = 0; s < 2; ++s) {
    int id = 2*t + s;
    int e = tope[id];
    int pos = off[e] + atomicAdd(&fill[e], 1);
    pair[pos] = id;   // order nondeterministic; ybuf row = id keeps output deterministic
  }
}

// ---------------- conversions ----------------
__global__ void k_hscvt(const float* __restrict__ src, _Float16* __restrict__ dst) {
  int i = blockIdx.x * blockDim.x + threadIdx.x;
  f32x4 v = ((const f32x4*)src)[i];
  f16x4 o;
  #pragma unroll
  for (int j = 0; j < 4; ++j) o[j] = (_Float16)v[j];
  ((f16x4*)dst)[i] = o;
}

// f32 [e][K][N] -> f16 [e][N][K], 64x64 tiles via LDS
__global__ __launch_bounds__(256) void k_wtrans(const float* __restrict__ src,
                                                _Float16* __restrict__ dst,
                                                int K, int N) {
  const int e = blockIdx.z;
  const int n0 = blockIdx.x * 64, k0 = blockIdx.y * 64;
  const float* s = src + (size_t)e * K * N;
  _Float16* d = dst + (size_t)e * (size_t)K * N;
  __shared__ _Float16 t[64][68];
  const int tx = threadIdx.x & 15, ty = threadIdx.x >> 4;
  #pragma unroll
  for (int it = 0; it < 4; ++it) {
    int k = k0 + it*16 + ty;
    f32x4 v = *(const f32x4*)&s[(size_t)k * N + n0 + tx*4];
    #pragma unroll
    for (int j = 0; j < 4; ++j) t[tx*4 + j][it*16 + ty] = (_Float16)v[j];
  }
  __syncthreads();
  #pragma unroll
  for (int it = 0; it < 4; ++it) {
    int n = it*16 + ty;
    *(f16x4*)&d[(size_t)(n0 + n) * K + k0 + tx*4] = *(const f16x4*)&t[n][tx*4];
  }
}

// ---------------- GEMM1: act[p] = silu(hs@Wg) * (hs@Wu), f16 ----------------
// (R6 structure, measured 178 us / MfmaUtil 38%)
// BM=256, BN=128 dual-B, BK=64; 8 waves (2M x 4N), wave tile 128x32 for g AND u.
// 1 block/CU, 128 KB dbuf LDS, 1 barrier + 1 vmcnt drain per K-tile.
__global__ __launch_bounds__(512, 2) void k_gemm1(
    const _Float16* __restrict__ hs16, const _Float16* __restrict__ WgT,
    const _Float16* __restrict__ WuT, char* __restrict__ ws) {
  const int s = blockIdx.y;
  if (s >= *(const int*)(ws + WS_TOT2)) return;
  const int e    = ((const int*)(ws + WS_TEXP2))[s];
  const int m0   = ((const int*)(ws + WS_TM02))[s];
  const int offE = ((const int*)(ws + WS_OFF))[e];
  const int nE   = ((const int*)(ws + WS_CNT))[e];
  _Float16* __restrict__ act = (_Float16*)(ws + WS_ACT);
  const int n0 = blockIdx.x * 128;
  const int tid = threadIdx.x, lane = tid & 63, wid = tid >> 6;

  // per buffer (f16 idx): A[256][64] @0 | Bg[128][64] @16384 | Bu[128][64] @24576
  __shared__ __align__(16) _Float16 sm[2 * 32768];   // 128 KB

  const int r8 = lane >> 3;
  const int q64 = (((lane & 7) ^ r8) << 3);   // inverse-swizzled source granule
  const int* __restrict__ pairp = (const int*)(ws + WS_PAIR);
  const _Float16 *aP[4], *gP[2], *uP[2];
  #pragma unroll
  for (int c = 0; c < 4; ++c) {        // A: wave stages rows 32w..32w+31
    int mm = m0 + 32*wid + 8*c + r8;
    int tok = (mm < nE) ? (pairp[offE + mm] >> 1) : 0;
    aP[c] = hs16 + (size_t)tok * HD + q64;
  }
  #pragma unroll
  for (int c = 0; c < 2; ++c) {        // B: wave stages cols 16w..16w+15
    size_t col = (size_t)e * ID + (n0 + 16*wid + 8*c + r8);
    gP[c] = WgT + col * HD + q64;
    uP[c] = WuT + col * HD + q64;
  }

  auto stage8 = [&](int buf, int kt) {   // 8 gll per wave per K-tile (128B lines)
    _Float16* base = sm + buf * 32768;
    const int ko = kt * 64;
    #pragma unroll
    for (int c = 0; c < 4; ++c)
      gll16(aP[c] + ko, base + (32*wid + 8*c) * 64);
    #pragma unroll
    for (int c = 0; c < 2; ++c) {
      gll16(gP[c] + ko, base + 16384 + (16*wid + 8*c) * 64);
      gll16(uP[c] + ko, base + 24576 + (16*wid + 8*c) * 64);
    }
  };

  const int wr = wid >> 2, wc = wid & 3;   // 2M x 4N
  const int l15 = lane & 15, l4 = lane >> 4;
  f32x4 accg[8][2] = {}, accu[8][2] = {};

  auto computeKK = [&](int buf, int kk) {  // one K=32 half: 12 reads, 32 MFMA
    const _Float16* b0 = sm + buf * 32768;
    f16x8 afr[8], bg[2], bu[2];
    #pragma unroll
    for (int i = 0; i < 8; ++i) {
      const int row = 128*wr + 16*i + l15;
      afr[i] = *(const f16x8*)&b0[lofs64(row, kk*4 + l4)];
    }
    #pragma unroll
    for (int j = 0; j < 2; ++j) {
      const int row = 32*wc + 16*j + l15;
      bg[j] = *(const f16x8*)&b0[16384 + lofs64(row, kk*4 + l4)];
      bu[j] = *(const f16x8*)&b0[24576 + lofs64(row, kk*4 + l4)];
    }
    __builtin_amdgcn_s_setprio(1);
    #pragma unroll
    for (int i = 0; i < 8; ++i)
      #pragma unroll
      for (int j = 0; j < 2; ++j) {
        accg[i][j] = __builtin_amdgcn_mfma_f32_16x16x32_f16(afr[i], bg[j], accg[i][j], 0, 0, 0);
        accu[i][j] = __builtin_amdgcn_mfma_f32_16x16x32_f16(afr[i], bu[j], accu[i][j], 0, 0, 0);
      }
    __builtin_amdgcn_s_setprio(0);
  };

  const int KT = HD / 64;                  // 16
  stage8(0, 0);
  WAITV(0);
  __builtin_amdgcn_s_barrier();
  for (int t = 0; t < KT; ++t) {
    const int cur = t & 1;
    if (t + 1 < KT) stage8(cur ^ 1, t + 1);  // issue early; retires under MFMA
    computeKK(cur, 0);
    computeKK(cur, 1);
    WAITV(0);                                // next tile fully landed
    __builtin_amdgcn_s_barrier();            // + everyone done reading cur
  }

  #pragma unroll
  for (int i = 0; i < 8; ++i)
    #pragma unroll
    for (int r = 0; r < 4; ++r) {
      const int mm = m0 + 128*wr + 16*i + 4*l4 + r;   // C/D: col=lane&15, row=(lane>>4)*4+r
      if (mm < nE) {
        const size_t prow = (size_t)(offE + mm) * ID;
        #pragma unroll
        for (int j = 0; j < 2; ++j) {
          float g = accg[i][j][r], u = accu[i][j][r];
          float sv = g / (1.f + __expf(-g)) * u;
          act[prow + n0 + 32*wc + 16*j + l15] = (_Float16)sv;
        }
      }
    }
}

// ---------------- GEMM2: yb[h][id] = act[p][kq] @ WdT[e][kq] (K-split 4) -----
// Clone of gemm1's R6 structure: BM=256, BN=256, BK=64; 8 waves (2M x 4N),
// wave tile 128x64; 128 KB dbuf; 8 full-line glls/wave/tile; drain-0/K-tile.
__global__ __launch_bounds__(512, 2) void k_gemm2(const _Float16* __restrict__ WdT,
                                                  char* __restrict__ ws) {
  const int s = blockIdx.y;
  if (s >= *(const int*)(ws + WS_TOT2)) return;
  const int e    = ((const int*)(ws + WS_TEXP2))[s];
  const int m0   = ((const int*)(ws + WS_TM02))[s];
  const int offE = ((const int*)(ws + WS_OFF))[e];
  const int nE   = ((const int*)(ws + WS_CNT))[e];
  const int h    = blockIdx.z;             // K quarter
  const int kbase = h * (ID / 4);
  const int* __restrict__ pair = (const int*)(ws + WS_PAIR);
  const _Float16* __restrict__ act = (const _Float16*)(ws + WS_ACT);
  _Float16* __restrict__ yb = (_Float16*)(ws + WS_YB) + (size_t)h * TOTP * HD;
  const int n0 = blockIdx.x * 256;
  const int tid = threadIdx.x, lane = tid & 63, wid = tid >> 6;

  // per buffer (f16 idx): A[256][64] @0 | B[256][64] @16384
  __shared__ __align__(16) _Float16 sm[2 * 32768];   // 128 KB

  const int r8 = lane >> 3;
  const int q64 = (((lane & 7) ^ r8) << 3);
  const _Float16 *aP[4], *bP[4];
  #pragma unroll
  for (int c = 0; c < 4; ++c) {        // A: wave stages rows 32w..32w+31
    int mm = m0 + 32*wid + 8*c + r8;
    int p = (mm < nE) ? (offE + mm) : offE;   // act rows ARE pair positions
    aP[c] = act + (size_t)p * ID + kbase + q64;
  }
  #pragma unroll
  for (int c = 0; c < 4; ++c)          // B: wave stages cols 32w..32w+31
    bP[c] = WdT + ((size_t)e * HD + (n0 + 32*wid + 8*c + r8)) * ID + kbase + q64;

  auto stage8 = [&](int buf, int kt) {   // 8 gll per wave per K-tile (128B lines)
    _Float16* base = sm + buf * 32768;
    const int ko = kt * 64;
    #pragma unroll
    for (int c = 0; c < 4; ++c)
      gll16(aP[c] + ko, base + (32*wid + 8*c) * 64);
    #pragma unroll
    for (int c = 0; c < 4; ++c)
      gll16(bP[c] + ko, base + 16384 + (32*wid + 8*c) * 64);
  };

  const int wr = wid >> 2, wc = wid & 3;   // 2M x 4N
  const int l15 = lane & 15, l4 = lane >> 4;
  f32x4 acc[8][4] = {};

  auto computeKK = [&](int buf, int kk) {  // one K=32 half: 12 reads, 32 MFMA
    const _Float16* b0 = sm + buf * 32768;
    f16x8 afr[8], bfr[4];
    #pragma unroll
    for (int i = 0; i < 8; ++i)
      afr[i] = *(const f16x8*)&b0[lofs64(128*wr + 16*i + l15, kk*4 + l4)];
    #pragma unroll
    for (int j = 0; j < 4; ++j)
      bfr[j] = *(const f16x8*)&b0[16384 + lofs64(64*wc + 16*j + l15, kk*4 + l4)];
    __builtin_amdgcn_s_setprio(1);
    #pragma unroll
    for (int i = 0; i < 8; ++i)
      #pragma unroll
      for (int j = 0; j < 4; ++j)
        acc[i][j] = __builtin_amdgcn_mfma_f32_16x16x32_f16(afr[i], bfr[j], acc[i][j], 0, 0, 0);
    __builtin_amdgcn_s_setprio(0);
  };

  const int KT = (ID / 4) / 64;            // 16
  stage8(0, 0);
  WAITV(0);
  __builtin_amdgcn_s_barrier();
  for (int t = 0; t < KT; ++t) {
    const int cur = t & 1;
    if (t + 1 < KT) stage8(cur ^ 1, t + 1);
    computeKK(cur, 0);
    computeKK(cur, 1);
    WAITV(0);
    __builtin_amdgcn_s_barrier();
  }

  #pragma unroll
  for (int i = 0; i < 8; ++i)
    #pragma unroll
    for (int r = 0; r < 4; ++r) {
      const int mm = m0 + 128*wr + 16*i + 4*l4 + r;
      if (mm < nE) {
        const int id = pair[offE + mm];
        #pragma unroll
        for (int j = 0; j < 4; ++j)
          yb[(size_t)id * HD + n0 + 64*wc + 16*j + l15] = (_Float16)acc[i][j][r];
      }
    }
}

// ---------------- combine: out[t] = w0*sum_h(y[h][2t]) + w1*sum_h(y[h][2t+1])
__global__ void k_combine(const char* __restrict__ ws, float* __restrict__ out) {
  const int idx = blockIdx.x * blockDim.x + threadIdx.x;   // over T*HD/8
  const int t = idx >> 7, c = idx & 127;
  const float* topw = (const float*)(ws + WS_TOPW);
  const _Float16* yb = (const _Float16*)(ws + WS_YB);
  float s0[8] = {}, s1[8] = {};
  #pragma unroll
  for (int h = 0; h < 4; ++h) {
    const _Float16* p = yb + (size_t)h * TOTP * HD;
    f16x8 y0 = ((const f16x8*)(p + (size_t)(2*t)     * HD))[c];
    f16x8 y1 = ((const f16x8*)(p + (size_t)(2*t + 1) * HD))[c];
    #pragma unroll
    for (int j = 0; j < 8; ++j) { s0[j] += (float)y0[j]; s1[j] += (float)y1[j]; }
  }
  const float w0 = topw[2*t], w1 = topw[2*t+1];
  f32x4 o0, o1;
  #pragma unroll
  for (int j = 0; j < 4; ++j) {
    o0[j] = w0 * s0[j]     + w1 * s1[j];
    o1[j] = w0 * s0[4 + j] + w1 * s1[4 + j];
  }
  ((f32x4*)out)[2*idx]     = o0;
  ((f32x4*)out)[2*idx + 1] = o1;
}

extern "C" void kernel_launch(void* const* d_in, const int* in_sizes, int n_in,
                              void* d_out, int out_size, void* d_ws, size_t ws_size,
                              hipStream_t stream) {
  const float* hs     = (const float*)d_in[0];
  const float* logits = (const float*)d_in[1];
  const float* Wg     = (const float*)d_in[2];
  const float* Wu     = (const float*)d_in[3];
  const float* Wd     = (const float*)d_in[4];
  char* ws = (char*)d_ws;   // requires ~295 MB of workspace

  _Float16* hs16 = (_Float16*)(ws + WS_HS16);
  _Float16* wg16 = (_Float16*)(ws + WS_WG16);
  _Float16* wu16 = (_Float16*)(ws + WS_WU16);
  _Float16* wd16 = (_Float16*)(ws + WS_WD16);

  hipMemsetAsync(ws, 0, 256, stream);
  k_router <<<dim3(T_TOK/256), dim3(256), 0, stream>>>(logits, ws);
  k_prefix <<<dim3(1),         dim3(64),  0, stream>>>(ws);
  k_scatter<<<dim3(T_TOK/256), dim3(256), 0, stream>>>(ws);
  k_hscvt  <<<dim3(T_TOK*HD/4/256), dim3(256), 0, stream>>>(hs, hs16);
  k_wtrans <<<dim3(ID/64, HD/64, NE), dim3(256), 0, stream>>>(Wg, wg16, HD, ID);
  k_wtrans <<<dim3(ID/64, HD/64, NE), dim3(256), 0, stream>>>(Wu, wu16, HD, ID);
  k_wtrans <<<dim3(HD/64, ID/64, NE), dim3(256), 0, stream>>>(Wd, wd16, ID, HD);
  k_gemm1  <<<dim3(ID/128, MAXT2),    dim3(512), 0, stream>>>(hs16, wg16, wu16, ws);
  k_gemm2  <<<dim3(HD/256, MAXT2, 4), dim3(512), 0, stream>>>(wd16, ws);
  k_combine<<<dim3(T_TOK*HD/8/256), dim3(256), 0, stream>>>(ws, (float*)d_out);
}